// Round 5
// baseline (188.302 us; speedup 1.0000x reference)
//
#include <hip/hip_runtime.h>
#include <hip/hip_fp16.h>
#include <math.h>

#define SP 32768            // 32*32*32 voxels
#define PW 38               // padded volume width (zero ring around 34^3 logical)
#define PW2 (PW*PW)         // 1444
#define PVOX (PW*PW*PW)     // 54872
#define OMS 228             // om_s row stride (floats): 28-pt padded offs(2*84) + masks(2*28)

typedef short bf16x8 __attribute__((ext_vector_type(8)));
typedef unsigned short u16x4 __attribute__((ext_vector_type(4)));
typedef float f32x4 __attribute__((ext_vector_type(4)));

__device__ __forceinline__ unsigned short f2b(float f) {
    unsigned u = __float_as_uint(f);
    u = (u + 0x7FFFu + ((u >> 16) & 1u)) >> 16;   // RNE
    return (unsigned short)u;
}
__device__ __forceinline__ float b2f1(unsigned short s) {
    return __uint_as_float(((unsigned)s) << 16);
}
__device__ __forceinline__ __half2 h2(unsigned u) {
    return *reinterpret_cast<__half2*>(&u);
}
// block voxel tile = 2(d) x 2(h) x 2(w); tile grid = 16 x 16 x 16 = 4096 blocks
__device__ __forceinline__ int vox_of(int sb, int v) {
    int tw = sb & 15, th = (sb >> 4) & 15, td = sb >> 8;
    int vw = v & 1, vh = (v >> 1) & 1, vd = (v >> 2) & 1;
    return (((td << 1) + vd) << 10) + (((th << 1) + vh) << 5) + (tw << 1) + vw;
}

// ====== K1: prep (bf16 B^T weights) + x transpose + dwconv(x4) + ring zero ======
__global__ void k_front(const float* __restrict__ x, const float* __restrict__ dw,
                        const float* __restrict__ off_w, const float* __restrict__ mask_w,
                        const float* __restrict__ off_b, const float* __restrict__ mask_b,
                        const float* __restrict__ inp_w, const float* __restrict__ out_w,
                        unsigned short* __restrict__ WcatB, float* __restrict__ bcat,
                        unsigned short* __restrict__ inpB, unsigned short* __restrict__ outB,
                        unsigned short* __restrict__ x_tb,
                        unsigned short* __restrict__ xcb, float* __restrict__ partials,
                        unsigned short* __restrict__ xpad) {
    int bb = blockIdx.x, tid = threadIdx.x;
    if (bb < 88) {                               // ---- weight prep ----
        int idx = bb * 256 + tid;
        int j = idx >> 6, k = idx & 63;
        if (j < 224) {
            float v = 0.f;
            if (j < 162) v = off_w[k * 162 + j];
            else if (j < 216) v = mask_w[k * 54 + (j - 162)];
            WcatB[j * 64 + k] = f2b(v);
            if (k == 0) bcat[j] = (j < 162) ? off_b[j] : (j < 216 ? mask_b[j - 162] : 0.f);
        } else if (j < 288) {
            outB[(j - 224) * 64 + k] = f2b(out_w[k * 64 + (j - 224)]);
        } else {
            inpB[(j - 288) * 64 + k] = f2b(inp_w[k * 64 + (j - 288)]);
        }
        return;
    }
    if (bb < 600) {                              // ---- x: NCDHW -> [s][c] bf16 ----
        __shared__ unsigned short tile[64][66];
        int s0 = (bb - 88) * 64;
        int row = tid >> 6, lane = tid & 63;
        for (int c = row; c < 64; c += 4)
            tile[c][lane] = f2b(x[(size_t)c * SP + s0 + lane]);
        __syncthreads();
        for (int r = row; r < 64; r += 4)
            x_tb[(size_t)(s0 + r) * 64 + lane] = tile[lane][r];
        return;
    }
    if (bb < 2648) {                             // ---- dwconv 3x3x3, 4 outputs/thread ----
        int b4 = bb - 600;
        int e4 = b4 * 256 + tid;                 // group of 4 voxels along w
        int c = e4 >> 13, s4 = (e4 & 8191) << 2;
        int d = s4 >> 10, h = (s4 >> 5) & 31, w0 = s4 & 31;   // w0 in {0,4,...,28}
        const float* xs = x + (size_t)c * SP;
        const float* wt = dw + c * 27;
        float a0 = 0.f, a1 = 0.f, a2 = 0.f, a3 = 0.f;
#pragma unroll
        for (int kd = 0; kd < 3; ++kd) {
            int zz = d + kd - 1; if ((unsigned)zz >= 32u) continue;
#pragma unroll
            for (int kh = 0; kh < 3; ++kh) {
                int yy = h + kh - 1; if ((unsigned)yy >= 32u) continue;
                const float* row = xs + (zz << 10) + (yy << 5) + w0;
                float4 L = *(const float4*)row;
                float xl = (w0 > 0) ? row[-1] : 0.f;
                float xr = (w0 < 28) ? row[4] : 0.f;
                const float* wr = wt + kd * 9 + kh * 3;
                float wm = wr[0], wc = wr[1], wp = wr[2];
                a0 = __builtin_fmaf(wm, xl,  __builtin_fmaf(wc, L.x, __builtin_fmaf(wp, L.y, a0)));
                a1 = __builtin_fmaf(wm, L.x, __builtin_fmaf(wc, L.y, __builtin_fmaf(wp, L.z, a1)));
                a2 = __builtin_fmaf(wm, L.y, __builtin_fmaf(wc, L.z, __builtin_fmaf(wp, L.w, a2)));
                a3 = __builtin_fmaf(wm, L.z, __builtin_fmaf(wc, L.w, __builtin_fmaf(wp, xr,  a3)));
            }
        }
        u16x4 o4; o4[0] = f2b(a0); o4[1] = f2b(a1); o4[2] = f2b(a2); o4[3] = f2b(a3);
        *(u16x4*)(xcb + (size_t)e4 * 4) = o4;
        __shared__ float rs[256], rq[256];
        rs[tid] = a0 + a1 + a2 + a3;
        rq[tid] = a0 * a0 + a1 * a1 + a2 * a2 + a3 * a3;
        __syncthreads();
        for (int off = 128; off > 0; off >>= 1) {
            if (tid < off) { rs[tid] += rs[tid + off]; rq[tid] += rq[tid + off]; }
            __syncthreads();
        }
        if (tid == 0) {
            partials[b4 * 2 + 0] = rs[0];
            partials[b4 * 2 + 1] = rq[0];
        }
        return;
    }
    // ---- ring zero (fp16): independent of everything else ----
    int cblk = bb - 2648;
    int j = tid >> 4, c4 = tid & 15;
    u16x4 z = {0, 0, 0, 0};
#pragma unroll
    for (int k = 0; k < 4; ++k) {
        int v = cblk * 64 + k * 16 + j;
        if (v >= PVOX) break;
        int zz = v / PW2, r = v - zz * PW2, yy = r / PW, xx = r - yy * PW;
        if (zz < 2 || zz > 33 || yy < 2 || yy > 33 || xx < 2 || xx > 33)
            *(u16x4*)(xpad + (size_t)v * 64 + c4 * 4) = z;
    }
}

// ========= K2: GN+GELU -> x1b  |  MFMA inproj -> xpad (fp16) =========
__global__ void k_mid(const unsigned short* __restrict__ xcb, const float* __restrict__ partials,
                      const float* __restrict__ gn_w, const float* __restrict__ gn_b,
                      unsigned short* __restrict__ x1b,
                      const unsigned short* __restrict__ x_tb,
                      const unsigned short* __restrict__ inpB,
                      const float* __restrict__ inp_b,
                      unsigned short* __restrict__ xpad) {
    int bb = blockIdx.x, tid = threadIdx.x;
    if (bb < 512) {                              // ---- GroupNorm(1,C)+GELU, transposed ----
        __shared__ float rs[256], rq[256];
        __shared__ unsigned short tile[64][66];
        float a = 0.f, b = 0.f;
        for (int i = tid; i < 2048; i += 256) { a += partials[2 * i]; b += partials[2 * i + 1]; }
        rs[tid] = a; rq[tid] = b;
        __syncthreads();
        for (int off = 128; off > 0; off >>= 1) {
            if (tid < off) { rs[tid] += rs[tid + off]; rq[tid] += rq[tid + off]; }
            __syncthreads();
        }
        const float Minv = 1.f / 2097152.f;
        float mu = rs[0] * Minv;
        float var = rq[0] * Minv - mu * mu;
        float rsq = rsqrtf(var + 1e-5f);
        int s0 = bb * 64;
        int row = tid >> 6, lane = tid & 63;
        for (int c = row; c < 64; c += 4) {
            float v = (b2f1(xcb[(size_t)c * SP + s0 + lane]) - mu) * rsq * gn_w[c] + gn_b[c];
            // gelu(tanh) = v * sigmoid(2t), t = 0.79788456*(v+0.044715 v^3)
            float t2 = 1.5957691216057308f * (v + 0.044715f * v * v * v);
            tile[c][lane] = f2b(v / (1.f + __expf(-t2)));
        }
        __syncthreads();
        for (int r = row; r < 64; r += 4)
            x1b[(size_t)(s0 + r) * 64 + lane] = tile[lane][r];
        return;
    }
    // ---- inproj: 4 waves x 16 voxels ----
    {
        int wv = tid >> 6, lane = tid & 63;
        int quad = lane >> 4, col = lane & 15;
        int s0 = (bb - 512) * 64 + wv * 16;
        bf16x8 a0 = *(const bf16x8*)(x_tb + (size_t)(s0 + col) * 64 + quad * 8);
        bf16x8 a1 = *(const bf16x8*)(x_tb + (size_t)(s0 + col) * 64 + 32 + quad * 8);
        int vp[4];
#pragma unroll
        for (int r = 0; r < 4; ++r) {
            int s = s0 + (quad << 2) + r;        // orig voxel (d,h,w) at 38-coord +2
            vp[r] = (((s >> 10) + 2) * PW + ((s >> 5) & 31) + 2) * PW + (s & 31) + 2;
        }
#pragma unroll
        for (int nt = 0; nt < 4; ++nt) {
            int n0 = nt * 16;
            bf16x8 b0 = *(const bf16x8*)(inpB + (n0 + col) * 64 + quad * 8);
            bf16x8 b1 = *(const bf16x8*)(inpB + (n0 + col) * 64 + 32 + quad * 8);
            f32x4 c = {0.f, 0.f, 0.f, 0.f};
            c = __builtin_amdgcn_mfma_f32_16x16x32_bf16(a0, b0, c, 0, 0, 0);
            c = __builtin_amdgcn_mfma_f32_16x16x32_bf16(a1, b1, c, 0, 0, 0);
            float bq = inp_b[n0 + col];
#pragma unroll
            for (int r = 0; r < 4; ++r)
                xpad[(size_t)vp[r] * 64 + n0 + col] =
                    __half_as_ushort(__float2half(c[r] + bq));
        }
    }
}

// ---- 27-point sampler, 4 fp16 channels/lane (uint2 loads, 2 half2 lanes of math) ----
__device__ __forceinline__ void sample27_4(const float* __restrict__ orow,
                                           const float* __restrict__ mrow,
                                           const char* __restrict__ volc,
                                           float xb, float yb, float zb,
                                           float* __restrict__ acc) {
#pragma unroll
    for (int p = 0; p < 27; ++p) {
        const int px = p % 3, py = (p / 3) % 3, pz = p / 9;
        float ox = orow[p * 3 + 0], oy = orow[p * 3 + 1], oz = orow[p * 3 + 2];
        float mk = mrow[p];
        float ix = __builtin_fmaf(0.25f, ox, xb + (float)px);
        float iy = __builtin_fmaf(0.5f, oy, yb + (float)py);
        float iz = __builtin_fmaf(0.5f, oz, zb + (float)pz);
        // clamp to [0,36]: OOB samples land wholly in the zero ring
        ix = fminf(fmaxf(ix, 0.f), 36.f);
        iy = fminf(fmaxf(iy, 0.f), 36.f);
        iz = fminf(fmaxf(iz, 0.f), 36.f);
        float xf = floorf(ix), yf = floorf(iy), zf = floorf(iz);
        float fx = ix - xf, fy = iy - yf, fz = iz - zf;
        float fi = __builtin_fmaf(zf, (float)PW2, __builtin_fmaf(yf, (float)PW, xf));
        int ib = ((int)fi) << 7;                 // 128 B per voxel row (fp16)
        const char* base = volc + ib;
        uint2 r000 = *(const uint2*)(base);
        uint2 r001 = *(const uint2*)(base + 128);
        uint2 r010 = *(const uint2*)(base + PW * 128);
        uint2 r011 = *(const uint2*)(base + PW * 128 + 128);
        uint2 r100 = *(const uint2*)(base + PW2 * 128);
        uint2 r101 = *(const uint2*)(base + PW2 * 128 + 128);
        uint2 r110 = *(const uint2*)(base + (PW2 + PW) * 128);
        uint2 r111 = *(const uint2*)(base + (PW2 + PW) * 128 + 128);
        __half2 fx2 = __float2half2_rn(fx);
        __half2 fy2 = __float2half2_rn(fy);
        __half2 fz2 = __float2half2_rn(fz);
        #define TRI(comp, ci)                                                   \
        {                                                                       \
            __half2 t0 = __hfma2(fx2, __hsub2(h2(r001.comp), h2(r000.comp)), h2(r000.comp)); \
            __half2 t1 = __hfma2(fx2, __hsub2(h2(r011.comp), h2(r010.comp)), h2(r010.comp)); \
            __half2 t2 = __hfma2(fx2, __hsub2(h2(r101.comp), h2(r100.comp)), h2(r100.comp)); \
            __half2 t3 = __hfma2(fx2, __hsub2(h2(r111.comp), h2(r110.comp)), h2(r110.comp)); \
            __half2 u0 = __hfma2(fy2, __hsub2(t1, t0), t0);                     \
            __half2 u1 = __hfma2(fy2, __hsub2(t3, t2), t2);                     \
            __half2 rr = __hfma2(fz2, __hsub2(u1, u0), u0);                     \
            float2 ff = __half22float2(rr);                                     \
            acc[2 * ci + 0] = __builtin_fmaf(mk, ff.x, acc[2 * ci + 0]);        \
            acc[2 * ci + 1] = __builtin_fmaf(mk, ff.y, acc[2 * ci + 1]);        \
        }
        TRI(x, 0) TRI(y, 1)
        #undef TRI
    }
}

// ========= K3: main — 8 vox/block (2x2x2 tile), 2 waves, 4 ch/lane =========
// 4096 blocks x 2 waves = 8 waves/SIMD target; 2 barriers; in-wave softmax.
__global__ void __launch_bounds__(128, 4) k_main(const unsigned short* __restrict__ x1b,
                                                 const unsigned short* __restrict__ xpad,
                                                 const unsigned short* __restrict__ WcatB,
                                                 const float* __restrict__ bcat,
                                                 const unsigned short* __restrict__ outB,
                                                 const float* __restrict__ out_b,
                                                 float* __restrict__ out) {
    __shared__ float om_s[8 * OMS];              // 7296 B: 28-pt padded offs+masks
    __shared__ unsigned short smb[8 * 72];       // 1152 B: sampled accum, bf16 (stride 72)
    int tid = threadIdx.x, wv = tid >> 6, lane = tid & 63;
    int quad = lane >> 4, col = lane & 15;
    // XCD swizzle: blocks sharing (blk&7) land on one XCD, contiguous tile slab
    int sb = ((blockIdx.x & 7) << 9) | (blockIdx.x >> 3);
    // ---- phase 1: offset+mask GEMM (8x64)@(64x224), 16-row MFMA with dup rows ----
    {
        int sv = vox_of(sb, col & 7);            // rows 8-15 duplicate rows 0-7
        bf16x8 a0 = *(const bf16x8*)(x1b + (size_t)sv * 64 + quad * 8);
        bf16x8 a1 = *(const bf16x8*)(x1b + (size_t)sv * 64 + 32 + quad * 8);
        for (int jt = wv; jt < 14; jt += 2) {
            int n0 = jt * 16;
            bf16x8 b0 = *(const bf16x8*)(WcatB + (n0 + col) * 64 + quad * 8);
            bf16x8 b1 = *(const bf16x8*)(WcatB + (n0 + col) * 64 + 32 + quad * 8);
            f32x4 c = {0.f, 0.f, 0.f, 0.f};
            c = __builtin_amdgcn_mfma_f32_16x16x32_bf16(a0, b0, c, 0, 0, 0);
            c = __builtin_amdgcn_mfma_f32_16x16x32_bf16(a1, b1, c, 0, 0, 0);
            float bb = bcat[n0 + col];
            // remap feature n -> padded 28-pt slot
            int n = n0 + col, slot;
            if (n < 162) slot = n + ((n >= 81) ? 3 : 0);
            else { int n2 = n - 162; slot = 168 + n2 + ((n2 >= 27) ? 1 : 0); }
            if (n < 216 && quad < 2) {           // output rows 0-7 only (8 voxels)
#pragma unroll
                for (int r = 0; r < 4; ++r)
                    om_s[(quad * 4 + r) * OMS + slot] = c[r] + bb;
            }
        }
    }
    __syncthreads();
    // ---- phase 2: wave-parallel softmax; 8 rows/wave (4 vox x 2 grp), 8 lanes/row ----
    // Same wave consumes its own rows in phase 3 -> no barrier needed after this.
    {
        int row = lane >> 3, sub = lane & 7;     // 8 lanes per row, 4 pts per lane
        int vloc = wv * 4 + (row >> 1), g = row & 1;
        float* m = &om_s[vloc * OMS + 168 + g * 28];
        float mv[4];
        float mx = -1e30f;
#pragma unroll
        for (int i = 0; i < 4; ++i) {
            int p = sub * 4 + i;
            mv[i] = (p < 27) ? m[p] : -1e30f;
            mx = fmaxf(mx, mv[i]);
        }
        mx = fmaxf(mx, __shfl_xor(mx, 1));
        mx = fmaxf(mx, __shfl_xor(mx, 2));
        mx = fmaxf(mx, __shfl_xor(mx, 4));
        float e[4], sm = 0.f;
#pragma unroll
        for (int i = 0; i < 4; ++i) { e[i] = __expf(mv[i] - mx); sm += e[i]; }
        sm += __shfl_xor(sm, 1);
        sm += __shfl_xor(sm, 2);
        sm += __shfl_xor(sm, 4);
        float inv = 1.f / sm;
#pragma unroll
        for (int i = 0; i < 4; ++i) {
            int p = sub * 4 + i;
            if (p < 27) m[p] = e[i] * inv;
        }
    }
    // ---- phase 3: sampling; wave wv owns voxels wv*4..wv*4+3; 4 fp16 ch/lane ----
    {
        int v = wv * 4 + (lane >> 4);            // local voxel 0..7
        int cs = lane & 15, gg = cs >> 3;        // channels cs*4..cs*4+3
        int sv = vox_of(sb, v);
        float zb = (float)((sv >> 10) + 1);
        float yb = (float)(((sv >> 5) & 31) + 1);
        float xb = (float)((sv & 31) + 1);
        const float* orow = &om_s[v * OMS + gg * 84];
        const float* mrow = &om_s[v * OMS + 168 + gg * 28];
        const char* volc = (const char*)xpad + cs * 8;      // 4 fp16 channels
        float acc[4] = {0.f, 0.f, 0.f, 0.f};
        sample27_4(orow, mrow, volc, xb, yb, zb, acc);
        u16x4 sb4;
#pragma unroll
        for (int k = 0; k < 4; ++k) sb4[k] = f2b(acc[k]);
        *(u16x4*)(smb + v * 72 + cs * 4) = sb4;
    }
    __syncthreads();
    // ---- phase 4: out projection (8x64)@(64x64), 16-row MFMA with dup rows ----
    // Store directly to global from MFMA regs; rows 0-7 only.
    {
        bf16x8 oa0 = *(const bf16x8*)(smb + (col & 7) * 72 + quad * 8);
        bf16x8 oa1 = *(const bf16x8*)(smb + (col & 7) * 72 + 32 + quad * 8);
        int vr[4];
#pragma unroll
        for (int r = 0; r < 4; ++r) vr[r] = vox_of(sb, (quad & 1) * 4 + r);
#pragma unroll
        for (int t = 0; t < 2; ++t) {
            int n0 = (wv + t * 2) * 16;
            bf16x8 b0 = *(const bf16x8*)(outB + (n0 + col) * 64 + quad * 8);
            bf16x8 b1 = *(const bf16x8*)(outB + (n0 + col) * 64 + 32 + quad * 8);
            f32x4 c = {0.f, 0.f, 0.f, 0.f};
            c = __builtin_amdgcn_mfma_f32_16x16x32_bf16(oa0, b0, c, 0, 0, 0);
            c = __builtin_amdgcn_mfma_f32_16x16x32_bf16(oa1, b1, c, 0, 0, 0);
            float bb = out_b[n0 + col];
            if (quad < 2) {
#pragma unroll
                for (int r = 0; r < 4; ++r)
                    out[(size_t)vr[r] * 64 + n0 + col] = c[r] + bb;
            }
        }
    }
}

extern "C" void kernel_launch(void* const* d_in, const int* in_sizes, int n_in,
                              void* d_out, int out_size, void* d_ws, size_t ws_size,
                              hipStream_t stream) {
    const float* x      = (const float*)d_in[0];
    const float* dw_w   = (const float*)d_in[1];
    const float* gn_w   = (const float*)d_in[2];
    const float* gn_b   = (const float*)d_in[3];
    const float* inp_w  = (const float*)d_in[4];
    const float* inp_b  = (const float*)d_in[5];
    const float* off_w  = (const float*)d_in[6];
    const float* off_b  = (const float*)d_in[7];
    const float* mask_w = (const float*)d_in[8];
    const float* mask_b = (const float*)d_in[9];
    const float* out_w  = (const float*)d_in[10];
    const float* out_b  = (const float*)d_in[11];

    char* B = (char*)d_ws;
    float*          partials = (float*)(B + 256);                // 64 KB region (uses 16 KB)
    unsigned short* xcb      = (unsigned short*)(B + 65792);     // 4 MB (bf16)
    unsigned short* x1b      = (unsigned short*)(B + 8454400);   // 4 MB
    unsigned short* x_tb     = (unsigned short*)(B + 12648704);  // 4 MB
    unsigned short* xpad     = (unsigned short*)(B + 16843008);  // 7.02 MB (fp16)
    unsigned short* WcatB    = (unsigned short*)(B + 30890240);  // 28 KB
    float*          bcat     = (float*)(B + 30918912);           // 1 KB
    unsigned short* inpB     = (unsigned short*)(B + 30919936);  // 8 KB
    unsigned short* outB     = (unsigned short*)(B + 30928128);  // 8 KB
    float* out = (float*)d_out;

    k_front<<<88 + 512 + 2048 + 858, 256, 0, stream>>>(x, dw_w, off_w, mask_w, off_b, mask_b,
                                                       inp_w, out_w, WcatB, bcat, inpB, outB,
                                                       x_tb, xcb, partials, xpad);
    k_mid<<<512 + 512, 256, 0, stream>>>(xcb, partials, gn_w, gn_b, x1b,
                                         x_tb, inpB, inp_b, xpad);
    k_main<<<4096, 128, 0, stream>>>(x1b, xpad, WcatB, bcat, outB, out_b, out);
}

// Round 6
// 156.505 us; speedup vs baseline: 1.2032x; 1.2032x over previous
//
#include <hip/hip_runtime.h>
#include <hip/hip_fp16.h>
#include <math.h>

#define SP 32768            // 32*32*32 voxels
#define PW 38               // padded volume width (zero ring around 34^3 logical)
#define PW2 (PW*PW)         // 1444
#define PVOX (PW*PW*PW)     // 54872
#define OMS 228             // om_s row stride (floats): 28-pt padded offs(2*84) + masks(2*28)

typedef short bf16x8 __attribute__((ext_vector_type(8)));
typedef unsigned short u16x4 __attribute__((ext_vector_type(4)));
typedef float f32x4 __attribute__((ext_vector_type(4)));

__device__ __forceinline__ unsigned short f2b(float f) {
    unsigned u = __float_as_uint(f);
    u = (u + 0x7FFFu + ((u >> 16) & 1u)) >> 16;   // RNE
    return (unsigned short)u;
}
__device__ __forceinline__ float b2f1(unsigned short s) {
    return __uint_as_float(((unsigned)s) << 16);
}
__device__ __forceinline__ __half2 h2(unsigned u) {
    return *reinterpret_cast<__half2*>(&u);
}
// block voxel tile = 2(d) x 2(h) x 4(w); tile grid = 16(d) x 16(h) x 8(w)
__device__ __forceinline__ int vox_of(int sb, int v) {
    int tw = sb & 7, th = (sb >> 3) & 15, td = sb >> 7;
    int vw = v & 3, vh = (v >> 2) & 1, vd = v >> 3;
    return (((td << 1) + vd) << 10) + (((th << 1) + vh) << 5) + (tw << 2) + vw;
}

// ====== K1: prep (bf16 B^T weights) + x transpose + dwconv(x4) + ring zero ======
__global__ void k_front(const float* __restrict__ x, const float* __restrict__ dw,
                        const float* __restrict__ off_w, const float* __restrict__ mask_w,
                        const float* __restrict__ off_b, const float* __restrict__ mask_b,
                        const float* __restrict__ inp_w, const float* __restrict__ out_w,
                        unsigned short* __restrict__ WcatB, float* __restrict__ bcat,
                        unsigned short* __restrict__ inpB, unsigned short* __restrict__ outB,
                        unsigned short* __restrict__ x_tb,
                        unsigned short* __restrict__ xcb, float* __restrict__ partials,
                        unsigned short* __restrict__ xpad) {
    int bb = blockIdx.x, tid = threadIdx.x;
    if (bb < 88) {                               // ---- weight prep ----
        int idx = bb * 256 + tid;
        int j = idx >> 6, k = idx & 63;
        if (j < 224) {
            float v = 0.f;
            if (j < 162) v = off_w[k * 162 + j];
            else if (j < 216) v = mask_w[k * 54 + (j - 162)];
            WcatB[j * 64 + k] = f2b(v);
            if (k == 0) bcat[j] = (j < 162) ? off_b[j] : (j < 216 ? mask_b[j - 162] : 0.f);
        } else if (j < 288) {
            outB[(j - 224) * 64 + k] = f2b(out_w[k * 64 + (j - 224)]);
        } else {
            inpB[(j - 288) * 64 + k] = f2b(inp_w[k * 64 + (j - 288)]);
        }
        return;
    }
    if (bb < 600) {                              // ---- x: NCDHW -> [s][c] bf16 ----
        __shared__ unsigned short tile[64][66];
        int s0 = (bb - 88) * 64;
        int row = tid >> 6, lane = tid & 63;
        for (int c = row; c < 64; c += 4)
            tile[c][lane] = f2b(x[(size_t)c * SP + s0 + lane]);
        __syncthreads();
        for (int r = row; r < 64; r += 4)
            x_tb[(size_t)(s0 + r) * 64 + lane] = tile[lane][r];
        return;
    }
    if (bb < 2648) {                             // ---- dwconv 3x3x3, 4 outputs/thread ----
        int b4 = bb - 600;
        int e4 = b4 * 256 + tid;                 // group of 4 voxels along w
        int c = e4 >> 13, s4 = (e4 & 8191) << 2;
        int d = s4 >> 10, h = (s4 >> 5) & 31, w0 = s4 & 31;   // w0 in {0,4,...,28}
        const float* xs = x + (size_t)c * SP;
        const float* wt = dw + c * 27;
        float a0 = 0.f, a1 = 0.f, a2 = 0.f, a3 = 0.f;
#pragma unroll
        for (int kd = 0; kd < 3; ++kd) {
            int zz = d + kd - 1; if ((unsigned)zz >= 32u) continue;
#pragma unroll
            for (int kh = 0; kh < 3; ++kh) {
                int yy = h + kh - 1; if ((unsigned)yy >= 32u) continue;
                const float* row = xs + (zz << 10) + (yy << 5) + w0;
                float4 L = *(const float4*)row;
                float xl = (w0 > 0) ? row[-1] : 0.f;
                float xr = (w0 < 28) ? row[4] : 0.f;
                const float* wr = wt + kd * 9 + kh * 3;
                float wm = wr[0], wc = wr[1], wp = wr[2];
                a0 = __builtin_fmaf(wm, xl,  __builtin_fmaf(wc, L.x, __builtin_fmaf(wp, L.y, a0)));
                a1 = __builtin_fmaf(wm, L.x, __builtin_fmaf(wc, L.y, __builtin_fmaf(wp, L.z, a1)));
                a2 = __builtin_fmaf(wm, L.y, __builtin_fmaf(wc, L.z, __builtin_fmaf(wp, L.w, a2)));
                a3 = __builtin_fmaf(wm, L.z, __builtin_fmaf(wc, L.w, __builtin_fmaf(wp, xr,  a3)));
            }
        }
        u16x4 o4; o4[0] = f2b(a0); o4[1] = f2b(a1); o4[2] = f2b(a2); o4[3] = f2b(a3);
        *(u16x4*)(xcb + (size_t)e4 * 4) = o4;
        __shared__ float rs[256], rq[256];
        rs[tid] = a0 + a1 + a2 + a3;
        rq[tid] = a0 * a0 + a1 * a1 + a2 * a2 + a3 * a3;
        __syncthreads();
        for (int off = 128; off > 0; off >>= 1) {
            if (tid < off) { rs[tid] += rs[tid + off]; rq[tid] += rq[tid + off]; }
            __syncthreads();
        }
        if (tid == 0) {
            partials[b4 * 2 + 0] = rs[0];
            partials[b4 * 2 + 1] = rq[0];
        }
        return;
    }
    // ---- ring zero (fp16): independent of everything else ----
    int cblk = bb - 2648;
    int j = tid >> 4, c4 = tid & 15;
    u16x4 z = {0, 0, 0, 0};
#pragma unroll
    for (int k = 0; k < 4; ++k) {
        int v = cblk * 64 + k * 16 + j;
        if (v >= PVOX) break;
        int zz = v / PW2, r = v - zz * PW2, yy = r / PW, xx = r - yy * PW;
        if (zz < 2 || zz > 33 || yy < 2 || yy > 33 || xx < 2 || xx > 33)
            *(u16x4*)(xpad + (size_t)v * 64 + c4 * 4) = z;
    }
}

// ========= K2: GN+GELU -> x1b  |  MFMA inproj -> xpad (fp16) =========
__global__ void k_mid(const unsigned short* __restrict__ xcb, const float* __restrict__ partials,
                      const float* __restrict__ gn_w, const float* __restrict__ gn_b,
                      unsigned short* __restrict__ x1b,
                      const unsigned short* __restrict__ x_tb,
                      const unsigned short* __restrict__ inpB,
                      const float* __restrict__ inp_b,
                      unsigned short* __restrict__ xpad) {
    int bb = blockIdx.x, tid = threadIdx.x;
    if (bb < 512) {                              // ---- GroupNorm(1,C)+GELU, transposed ----
        __shared__ float rs[256], rq[256];
        __shared__ unsigned short tile[64][66];
        float a = 0.f, b = 0.f;
        for (int i = tid; i < 2048; i += 256) { a += partials[2 * i]; b += partials[2 * i + 1]; }
        rs[tid] = a; rq[tid] = b;
        __syncthreads();
        for (int off = 128; off > 0; off >>= 1) {
            if (tid < off) { rs[tid] += rs[tid + off]; rq[tid] += rq[tid + off]; }
            __syncthreads();
        }
        const float Minv = 1.f / 2097152.f;
        float mu = rs[0] * Minv;
        float var = rq[0] * Minv - mu * mu;
        float rsq = rsqrtf(var + 1e-5f);
        int s0 = bb * 64;
        int row = tid >> 6, lane = tid & 63;
        for (int c = row; c < 64; c += 4) {
            float v = (b2f1(xcb[(size_t)c * SP + s0 + lane]) - mu) * rsq * gn_w[c] + gn_b[c];
            // gelu(tanh) = v * sigmoid(2t), t = 0.79788456*(v+0.044715 v^3)
            float t2 = 1.5957691216057308f * (v + 0.044715f * v * v * v);
            tile[c][lane] = f2b(v / (1.f + __expf(-t2)));
        }
        __syncthreads();
        for (int r = row; r < 64; r += 4)
            x1b[(size_t)(s0 + r) * 64 + lane] = tile[lane][r];
        return;
    }
    // ---- inproj: 4 waves x 16 voxels ----
    {
        int wv = tid >> 6, lane = tid & 63;
        int quad = lane >> 4, col = lane & 15;
        int s0 = (bb - 512) * 64 + wv * 16;
        bf16x8 a0 = *(const bf16x8*)(x_tb + (size_t)(s0 + col) * 64 + quad * 8);
        bf16x8 a1 = *(const bf16x8*)(x_tb + (size_t)(s0 + col) * 64 + 32 + quad * 8);
        int vp[4];
#pragma unroll
        for (int r = 0; r < 4; ++r) {
            int s = s0 + (quad << 2) + r;        // orig voxel (d,h,w) at 38-coord +2
            vp[r] = (((s >> 10) + 2) * PW + ((s >> 5) & 31) + 2) * PW + (s & 31) + 2;
        }
#pragma unroll
        for (int nt = 0; nt < 4; ++nt) {
            int n0 = nt * 16;
            bf16x8 b0 = *(const bf16x8*)(inpB + (n0 + col) * 64 + quad * 8);
            bf16x8 b1 = *(const bf16x8*)(inpB + (n0 + col) * 64 + 32 + quad * 8);
            f32x4 c = {0.f, 0.f, 0.f, 0.f};
            c = __builtin_amdgcn_mfma_f32_16x16x32_bf16(a0, b0, c, 0, 0, 0);
            c = __builtin_amdgcn_mfma_f32_16x16x32_bf16(a1, b1, c, 0, 0, 0);
            float bq = inp_b[n0 + col];
#pragma unroll
            for (int r = 0; r < 4; ++r)
                xpad[(size_t)vp[r] * 64 + n0 + col] =
                    __half_as_ushort(__float2half(c[r] + bq));
        }
    }
}

// ---- 27-point sampler reading the block's LDS-staged region ----
// Region = 6(z) x 6(y) x 8(x) rows of 128 B; row rr = 48*z + 8*y + x.
// Consecutive 8 lanes (one voxel) read one full contiguous row -> bank-conflict-free.
__device__ __forceinline__ void sample27_lds(const float* __restrict__ orow,
                                             const float* __restrict__ mrow,
                                             const char* __restrict__ volp,  // vol + oct*16
                                             float xb, float yb, float zb,   // local coords
                                             float* __restrict__ acc) {
#pragma unroll
    for (int p = 0; p < 27; ++p) {
        const int px = p % 3, py = (p / 3) % 3, pz = p / 9;
        float ox = orow[p * 3 + 0], oy = orow[p * 3 + 1], oz = orow[p * 3 + 2];
        float mk = mrow[p];
        float ix = __builtin_fmaf(0.25f, ox, xb + (float)px);
        float iy = __builtin_fmaf(0.5f, oy, yb + (float)py);
        float iz = __builtin_fmaf(0.5f, oz, zb + (float)pz);
        // clamp to region (1-voxel margin; equals global clamp for |off|<1)
        ix = fminf(fmaxf(ix, 0.f), 6.999f);
        iy = fminf(fmaxf(iy, 0.f), 4.999f);
        iz = fminf(fmaxf(iz, 0.f), 4.999f);
        float xf = floorf(ix), yf = floorf(iy), zf = floorf(iz);
        float fx = ix - xf, fy = iy - yf, fz = iz - zf;
        float fi = __builtin_fmaf(zf, 48.f, __builtin_fmaf(yf, 8.f, xf));
        int rr = (int)fi;
        #define RD(o) (*(const uint4*)(volp + ((rr + (o)) << 7)))
        uint4 r000 = RD(0);
        uint4 r001 = RD(1);
        uint4 r010 = RD(8);
        uint4 r011 = RD(9);
        uint4 r100 = RD(48);
        uint4 r101 = RD(49);
        uint4 r110 = RD(56);
        uint4 r111 = RD(57);
        #undef RD
        __half2 fx2 = __float2half2_rn(fx);
        __half2 fy2 = __float2half2_rn(fy);
        __half2 fz2 = __float2half2_rn(fz);
        #define TRI(comp, ci)                                                   \
        {                                                                       \
            __half2 t0 = __hfma2(fx2, __hsub2(h2(r001.comp), h2(r000.comp)), h2(r000.comp)); \
            __half2 t1 = __hfma2(fx2, __hsub2(h2(r011.comp), h2(r010.comp)), h2(r010.comp)); \
            __half2 t2 = __hfma2(fx2, __hsub2(h2(r101.comp), h2(r100.comp)), h2(r100.comp)); \
            __half2 t3 = __hfma2(fx2, __hsub2(h2(r111.comp), h2(r110.comp)), h2(r110.comp)); \
            __half2 u0 = __hfma2(fy2, __hsub2(t1, t0), t0);                     \
            __half2 u1 = __hfma2(fy2, __hsub2(t3, t2), t2);                     \
            __half2 rr2 = __hfma2(fz2, __hsub2(u1, u0), u0);                    \
            float2 ff = __half22float2(rr2);                                    \
            acc[2 * ci + 0] = __builtin_fmaf(mk, ff.x, acc[2 * ci + 0]);        \
            acc[2 * ci + 1] = __builtin_fmaf(mk, ff.y, acc[2 * ci + 1]);        \
        }
        TRI(x, 0) TRI(y, 1) TRI(z, 2) TRI(w, 3)
        #undef TRI
    }
}

// ========= K3: main — 2x2x4 tile/block; volume region staged to LDS =========
// Gathers run on the LDS pipe (ds_read_b128) instead of the VMEM address pipe,
// which round 0-5 evidence shows is the ~32cyc/instr limiter. 2 barriers.
__global__ void __launch_bounds__(128, 2) k_main(const unsigned short* __restrict__ x1b,
                                                 const unsigned short* __restrict__ xpad,
                                                 const unsigned short* __restrict__ WcatB,
                                                 const float* __restrict__ bcat,
                                                 const unsigned short* __restrict__ outB,
                                                 const float* __restrict__ out_b,
                                                 float* __restrict__ out) {
    __shared__ float om_s[16 * OMS];             // 14592 B: 28-pt padded offs+masks
    __shared__ unsigned short smb[16 * 72];      // 2304 B: sampled accum, bf16 (stride 72)
    __shared__ char vol[288 * 128];              // 36864 B: 6x6x8 rows of fp16[64]
    int tid = threadIdx.x, wv = tid >> 6, lane = tid & 63;
    int quad = lane >> 4, col = lane & 15;
    // XCD swizzle over tiles: blocks sharing (blk&7) land on one XCD
    int sb = ((blockIdx.x & 7) << 8) | (blockIdx.x >> 3);
    int tw = sb & 7, th = (sb >> 3) & 15, td = sb >> 7;
    // ---- phase 0: stage 6x6x8 region (2304 x 16B units; 18 per thread) ----
    {
        const char* xp = (const char*)xpad;
#pragma unroll
        for (int k = 0; k < 3; ++k) {
            uint4 t[6];
#pragma unroll
            for (int j = 0; j < 6; ++j) {
                int u = tid + (k * 6 + j) * 128;
                int rr = u >> 3, ch = u & 7;
                int dz = rr / 48, rem = rr - dz * 48, dy = rem >> 3, dx = rem & 7;
                int pv = ((2 * td + dz) * PW + (2 * th + dy)) * PW + 4 * tw + dx;
                t[j] = *(const uint4*)(xp + ((size_t)pv << 7) + (ch << 4));
            }
#pragma unroll
            for (int j = 0; j < 6; ++j) {
                int u = tid + (k * 6 + j) * 128;
                *(uint4*)(vol + (u << 4)) = t[j];   // u*16 == rr*128 + ch*16 (linear)
            }
        }
    }
    // ---- phase 1: offset+mask GEMM (16x64)@(64x224); 7 jt tiles per wave ----
    {
        int sv = vox_of(sb, col);                // lane's A-row voxel
        bf16x8 a0 = *(const bf16x8*)(x1b + (size_t)sv * 64 + quad * 8);
        bf16x8 a1 = *(const bf16x8*)(x1b + (size_t)sv * 64 + 32 + quad * 8);
        for (int jt = wv; jt < 14; jt += 2) {
            int n0 = jt * 16;
            bf16x8 b0 = *(const bf16x8*)(WcatB + (n0 + col) * 64 + quad * 8);
            bf16x8 b1 = *(const bf16x8*)(WcatB + (n0 + col) * 64 + 32 + quad * 8);
            f32x4 c = {0.f, 0.f, 0.f, 0.f};
            c = __builtin_amdgcn_mfma_f32_16x16x32_bf16(a0, b0, c, 0, 0, 0);
            c = __builtin_amdgcn_mfma_f32_16x16x32_bf16(a1, b1, c, 0, 0, 0);
            float bb = bcat[n0 + col];
            // remap feature n -> padded 28-pt slot
            int n = n0 + col, slot;
            if (n < 162) slot = n + ((n >= 81) ? 3 : 0);
            else { int n2 = n - 162; slot = 168 + n2 + ((n2 >= 27) ? 1 : 0); }
            if (n < 216) {
#pragma unroll
                for (int r = 0; r < 4; ++r)
                    om_s[(quad * 4 + r) * OMS + slot] = c[r] + bb;
            }
        }
    }
    __syncthreads();                             // covers stage->sample and om->softmax
    // ---- phase 2: wave-parallel softmax; 16 rows/wave (8 vox x 2 grp), 4 lanes/row ----
    // Same wave consumes its own rows in phase 3 -> no barrier needed after this.
    {
        int row = lane >> 2, sub = lane & 3;     // 4 lanes per row, 7 pts per lane
        int vloc = wv * 8 + (row >> 1), g = row & 1;
        float* m = &om_s[vloc * OMS + 168 + g * 28];
        float mv[7];
        float mx = -1e30f;
#pragma unroll
        for (int i = 0; i < 7; ++i) {
            int p = sub * 7 + i;
            mv[i] = (p < 27) ? m[p] : -1e30f;
            mx = fmaxf(mx, mv[i]);
        }
        mx = fmaxf(mx, __shfl_xor(mx, 1));
        mx = fmaxf(mx, __shfl_xor(mx, 2));
        float e[7], sm = 0.f;
#pragma unroll
        for (int i = 0; i < 7; ++i) { e[i] = __expf(mv[i] - mx); sm += e[i]; }
        sm += __shfl_xor(sm, 1);
        sm += __shfl_xor(sm, 2);
        float inv = 1.f / sm;
#pragma unroll
        for (int i = 0; i < 7; ++i) {
            int p = sub * 7 + i;
            if (p < 27) m[p] = e[i] * inv;
        }
    }
    // ---- phase 3: sampling from LDS; wave wv owns voxels wv*8..wv*8+7 ----
    {
        int v = wv * 8 + (lane >> 3);            // local voxel 0..15
        int oct = lane & 7, gg = oct >> 2;       // channels oct*8..oct*8+7
        int vw = v & 3, vh = (v >> 2) & 1, vd = v >> 3;
        float xb = (float)(vw + 1);              // local region coords
        float yb = (float)(vh + 1);
        float zb = (float)(vd + 1);
        const float* orow = &om_s[v * OMS + gg * 84];
        const float* mrow = &om_s[v * OMS + 168 + gg * 28];
        float acc[8] = {0.f, 0.f, 0.f, 0.f, 0.f, 0.f, 0.f, 0.f};
        sample27_lds(orow, mrow, vol + oct * 16, xb, yb, zb, acc);
        bf16x8 sb8;
#pragma unroll
        for (int k = 0; k < 8; ++k) sb8[k] = (short)f2b(acc[k]);
        *(bf16x8*)(smb + v * 72 + oct * 8) = sb8;
    }
    __syncthreads();
    // ---- phase 4: out projection (16x64)@(64x64); wave wv: col tiles wv, wv+2 ----
    // Store directly to global from MFMA regs (no obuf, no extra barrier).
    {
        bf16x8 oa0 = *(const bf16x8*)(smb + col * 72 + quad * 8);
        bf16x8 oa1 = *(const bf16x8*)(smb + col * 72 + 32 + quad * 8);
        int vr[4];
#pragma unroll
        for (int r = 0; r < 4; ++r) vr[r] = vox_of(sb, quad * 4 + r);
#pragma unroll
        for (int t = 0; t < 2; ++t) {
            int n0 = (wv + t * 2) * 16;
            bf16x8 b0 = *(const bf16x8*)(outB + (n0 + col) * 64 + quad * 8);
            bf16x8 b1 = *(const bf16x8*)(outB + (n0 + col) * 64 + 32 + quad * 8);
            f32x4 c = {0.f, 0.f, 0.f, 0.f};
            c = __builtin_amdgcn_mfma_f32_16x16x32_bf16(oa0, b0, c, 0, 0, 0);
            c = __builtin_amdgcn_mfma_f32_16x16x32_bf16(oa1, b1, c, 0, 0, 0);
            float bb = out_b[n0 + col];
#pragma unroll
            for (int r = 0; r < 4; ++r)
                out[(size_t)vr[r] * 64 + n0 + col] = c[r] + bb;
        }
    }
}

extern "C" void kernel_launch(void* const* d_in, const int* in_sizes, int n_in,
                              void* d_out, int out_size, void* d_ws, size_t ws_size,
                              hipStream_t stream) {
    const float* x      = (const float*)d_in[0];
    const float* dw_w   = (const float*)d_in[1];
    const float* gn_w   = (const float*)d_in[2];
    const float* gn_b   = (const float*)d_in[3];
    const float* inp_w  = (const float*)d_in[4];
    const float* inp_b  = (const float*)d_in[5];
    const float* off_w  = (const float*)d_in[6];
    const float* off_b  = (const float*)d_in[7];
    const float* mask_w = (const float*)d_in[8];
    const float* mask_b = (const float*)d_in[9];
    const float* out_w  = (const float*)d_in[10];
    const float* out_b  = (const float*)d_in[11];

    char* B = (char*)d_ws;
    float*          partials = (float*)(B + 256);                // 64 KB region (uses 16 KB)
    unsigned short* xcb      = (unsigned short*)(B + 65792);     // 4 MB (bf16)
    unsigned short* x1b      = (unsigned short*)(B + 8454400);   // 4 MB
    unsigned short* x_tb     = (unsigned short*)(B + 12648704);  // 4 MB
    unsigned short* xpad     = (unsigned short*)(B + 16843008);  // 7.02 MB (fp16)
    unsigned short* WcatB    = (unsigned short*)(B + 30890240);  // 28 KB
    float*          bcat     = (float*)(B + 30918912);           // 1 KB
    unsigned short* inpB     = (unsigned short*)(B + 30919936);  // 8 KB
    unsigned short* outB     = (unsigned short*)(B + 30928128);  // 8 KB
    float* out = (float*)d_out;

    k_front<<<88 + 512 + 2048 + 858, 256, 0, stream>>>(x, dw_w, off_w, mask_w, off_b, mask_b,
                                                       inp_w, out_w, WcatB, bcat, inpB, outB,
                                                       x_tb, xcb, partials, xpad);
    k_mid<<<512 + 512, 256, 0, stream>>>(xcb, partials, gn_w, gn_b, x1b,
                                         x_tb, inpB, inp_b, xpad);
    k_main<<<2048, 128, 0, stream>>>(x1b, xpad, WcatB, bcat, outB, out_b, out);
}

// Round 7
// 152.778 us; speedup vs baseline: 1.2325x; 1.0244x over previous
//
#include <hip/hip_runtime.h>
#include <hip/hip_fp16.h>
#include <math.h>

#define SP 32768            // 32*32*32 voxels
#define PW 38               // padded volume width (zero ring around 34^3 logical)
#define PW2 (PW*PW)         // 1444
#define PVOX (PW*PW*PW)     // 54872
#define OMS 228             // om_s row stride (floats): 28-pt padded offs(2*84) + masks(2*28)

typedef short bf16x8 __attribute__((ext_vector_type(8)));
typedef unsigned short u16x4 __attribute__((ext_vector_type(4)));
typedef float f32x4 __attribute__((ext_vector_type(4)));

__device__ __forceinline__ unsigned short f2b(float f) {
    unsigned u = __float_as_uint(f);
    u = (u + 0x7FFFu + ((u >> 16) & 1u)) >> 16;   // RNE
    return (unsigned short)u;
}
__device__ __forceinline__ float b2f1(unsigned short s) {
    return __uint_as_float(((unsigned)s) << 16);
}
__device__ __forceinline__ __half2 h2(unsigned u) {
    return *reinterpret_cast<__half2*>(&u);
}
// block voxel tile = 2(d) x 2(h) x 4(w); tile grid = 16(d) x 16(h) x 8(w)
__device__ __forceinline__ int vox_of(int sb, int v) {
    int tw = sb & 7, th = (sb >> 3) & 15, td = sb >> 7;
    int vw = v & 3, vh = (v >> 2) & 1, vd = v >> 3;
    return (((td << 1) + vd) << 10) + (((th << 1) + vh) << 5) + (tw << 2) + vw;
}

// ====== K1: prep (bf16 B^T weights) + x transpose + dwconv(x4) + ring zero ======
__global__ void k_front(const float* __restrict__ x, const float* __restrict__ dw,
                        const float* __restrict__ off_w, const float* __restrict__ mask_w,
                        const float* __restrict__ off_b, const float* __restrict__ mask_b,
                        const float* __restrict__ inp_w, const float* __restrict__ out_w,
                        unsigned short* __restrict__ WcatB, float* __restrict__ bcat,
                        unsigned short* __restrict__ inpB, unsigned short* __restrict__ outB,
                        unsigned short* __restrict__ x_tb,
                        unsigned short* __restrict__ xcb, float* __restrict__ partials,
                        unsigned short* __restrict__ xpad) {
    int bb = blockIdx.x, tid = threadIdx.x;
    if (bb < 88) {                               // ---- weight prep ----
        int idx = bb * 256 + tid;
        int j = idx >> 6, k = idx & 63;
        if (j < 224) {
            float v = 0.f;
            if (j < 162) v = off_w[k * 162 + j];
            else if (j < 216) v = mask_w[k * 54 + (j - 162)];
            WcatB[j * 64 + k] = f2b(v);
            if (k == 0) bcat[j] = (j < 162) ? off_b[j] : (j < 216 ? mask_b[j - 162] : 0.f);
        } else if (j < 288) {
            outB[(j - 224) * 64 + k] = f2b(out_w[k * 64 + (j - 224)]);
        } else {
            inpB[(j - 288) * 64 + k] = f2b(inp_w[k * 64 + (j - 288)]);
        }
        return;
    }
    if (bb < 600) {                              // ---- x: NCDHW -> [s][c] bf16 ----
        __shared__ unsigned short tile[64][66];
        int s0 = (bb - 88) * 64;
        int row = tid >> 6, lane = tid & 63;
        for (int c = row; c < 64; c += 4)
            tile[c][lane] = f2b(x[(size_t)c * SP + s0 + lane]);
        __syncthreads();
        for (int r = row; r < 64; r += 4)
            x_tb[(size_t)(s0 + r) * 64 + lane] = tile[lane][r];
        return;
    }
    if (bb < 2648) {                             // ---- dwconv 3x3x3, 4 outputs/thread ----
        int b4 = bb - 600;
        int e4 = b4 * 256 + tid;                 // group of 4 voxels along w
        int c = e4 >> 13, s4 = (e4 & 8191) << 2;
        int d = s4 >> 10, h = (s4 >> 5) & 31, w0 = s4 & 31;   // w0 in {0,4,...,28}
        const float* xs = x + (size_t)c * SP;
        const float* wt = dw + c * 27;
        float a0 = 0.f, a1 = 0.f, a2 = 0.f, a3 = 0.f;
#pragma unroll
        for (int kd = 0; kd < 3; ++kd) {
            int zz = d + kd - 1; if ((unsigned)zz >= 32u) continue;
#pragma unroll
            for (int kh = 0; kh < 3; ++kh) {
                int yy = h + kh - 1; if ((unsigned)yy >= 32u) continue;
                const float* row = xs + (zz << 10) + (yy << 5) + w0;
                float4 L = *(const float4*)row;
                float xl = (w0 > 0) ? row[-1] : 0.f;
                float xr = (w0 < 28) ? row[4] : 0.f;
                const float* wr = wt + kd * 9 + kh * 3;
                float wm = wr[0], wc = wr[1], wp = wr[2];
                a0 = __builtin_fmaf(wm, xl,  __builtin_fmaf(wc, L.x, __builtin_fmaf(wp, L.y, a0)));
                a1 = __builtin_fmaf(wm, L.x, __builtin_fmaf(wc, L.y, __builtin_fmaf(wp, L.z, a1)));
                a2 = __builtin_fmaf(wm, L.y, __builtin_fmaf(wc, L.z, __builtin_fmaf(wp, L.w, a2)));
                a3 = __builtin_fmaf(wm, L.z, __builtin_fmaf(wc, L.w, __builtin_fmaf(wp, xr,  a3)));
            }
        }
        u16x4 o4; o4[0] = f2b(a0); o4[1] = f2b(a1); o4[2] = f2b(a2); o4[3] = f2b(a3);
        *(u16x4*)(xcb + (size_t)e4 * 4) = o4;
        __shared__ float rs[256], rq[256];
        rs[tid] = a0 + a1 + a2 + a3;
        rq[tid] = a0 * a0 + a1 * a1 + a2 * a2 + a3 * a3;
        __syncthreads();
        for (int off = 128; off > 0; off >>= 1) {
            if (tid < off) { rs[tid] += rs[tid + off]; rq[tid] += rq[tid + off]; }
            __syncthreads();
        }
        if (tid == 0) {
            partials[b4 * 2 + 0] = rs[0];
            partials[b4 * 2 + 1] = rq[0];
        }
        return;
    }
    // ---- ring zero (fp16): independent of everything else ----
    int cblk = bb - 2648;
    int j = tid >> 4, c4 = tid & 15;
    u16x4 z = {0, 0, 0, 0};
#pragma unroll
    for (int k = 0; k < 4; ++k) {
        int v = cblk * 64 + k * 16 + j;
        if (v >= PVOX) break;
        int zz = v / PW2, r = v - zz * PW2, yy = r / PW, xx = r - yy * PW;
        if (zz < 2 || zz > 33 || yy < 2 || yy > 33 || xx < 2 || xx > 33)
            *(u16x4*)(xpad + (size_t)v * 64 + c4 * 4) = z;
    }
}

// ========= K2: GN+GELU -> x1b  |  MFMA inproj -> xpad (fp16) =========
__global__ void k_mid(const unsigned short* __restrict__ xcb, const float* __restrict__ partials,
                      const float* __restrict__ gn_w, const float* __restrict__ gn_b,
                      unsigned short* __restrict__ x1b,
                      const unsigned short* __restrict__ x_tb,
                      const unsigned short* __restrict__ inpB,
                      const float* __restrict__ inp_b,
                      unsigned short* __restrict__ xpad) {
    int bb = blockIdx.x, tid = threadIdx.x;
    if (bb < 512) {                              // ---- GroupNorm(1,C)+GELU, transposed ----
        __shared__ float rs[256], rq[256];
        __shared__ unsigned short tile[64][66];
        float a = 0.f, b = 0.f;
        for (int i = tid; i < 2048; i += 256) { a += partials[2 * i]; b += partials[2 * i + 1]; }
        rs[tid] = a; rq[tid] = b;
        __syncthreads();
        for (int off = 128; off > 0; off >>= 1) {
            if (tid < off) { rs[tid] += rs[tid + off]; rq[tid] += rq[tid + off]; }
            __syncthreads();
        }
        const float Minv = 1.f / 2097152.f;
        float mu = rs[0] * Minv;
        float var = rq[0] * Minv - mu * mu;
        float rsq = rsqrtf(var + 1e-5f);
        int s0 = bb * 64;
        int row = tid >> 6, lane = tid & 63;
        for (int c = row; c < 64; c += 4) {
            float v = (b2f1(xcb[(size_t)c * SP + s0 + lane]) - mu) * rsq * gn_w[c] + gn_b[c];
            // gelu(tanh) = v * sigmoid(2t), t = 0.79788456*(v+0.044715 v^3)
            float t2 = 1.5957691216057308f * (v + 0.044715f * v * v * v);
            tile[c][lane] = f2b(v / (1.f + __expf(-t2)));
        }
        __syncthreads();
        for (int r = row; r < 64; r += 4)
            x1b[(size_t)(s0 + r) * 64 + lane] = tile[lane][r];
        return;
    }
    // ---- inproj: 4 waves x 16 voxels ----
    {
        int wv = tid >> 6, lane = tid & 63;
        int quad = lane >> 4, col = lane & 15;
        int s0 = (bb - 512) * 64 + wv * 16;
        bf16x8 a0 = *(const bf16x8*)(x_tb + (size_t)(s0 + col) * 64 + quad * 8);
        bf16x8 a1 = *(const bf16x8*)(x_tb + (size_t)(s0 + col) * 64 + 32 + quad * 8);
        int vp[4];
#pragma unroll
        for (int r = 0; r < 4; ++r) {
            int s = s0 + (quad << 2) + r;        // orig voxel (d,h,w) at 38-coord +2
            vp[r] = (((s >> 10) + 2) * PW + ((s >> 5) & 31) + 2) * PW + (s & 31) + 2;
        }
#pragma unroll
        for (int nt = 0; nt < 4; ++nt) {
            int n0 = nt * 16;
            bf16x8 b0 = *(const bf16x8*)(inpB + (n0 + col) * 64 + quad * 8);
            bf16x8 b1 = *(const bf16x8*)(inpB + (n0 + col) * 64 + 32 + quad * 8);
            f32x4 c = {0.f, 0.f, 0.f, 0.f};
            c = __builtin_amdgcn_mfma_f32_16x16x32_bf16(a0, b0, c, 0, 0, 0);
            c = __builtin_amdgcn_mfma_f32_16x16x32_bf16(a1, b1, c, 0, 0, 0);
            float bq = inp_b[n0 + col];
#pragma unroll
            for (int r = 0; r < 4; ++r)
                xpad[(size_t)vp[r] * 64 + n0 + col] =
                    __half_as_ushort(__float2half(c[r] + bq));
        }
    }
}

// ---- VMEM sampler (proven round-4 path); global coords, clamp [0,36] ----
template<int P0, int NP>
__device__ __forceinline__ void sampleN(const float* __restrict__ orow,
                                        const float* __restrict__ mrow,
                                        const char* __restrict__ volc,
                                        float xb, float yb, float zb,
                                        float* __restrict__ acc) {
#pragma unroll
    for (int i = 0; i < NP; ++i) {
        const int p = P0 + i;
        const int px = p % 3, py = (p / 3) % 3, pz = p / 9;
        float ox = orow[p * 3 + 0], oy = orow[p * 3 + 1], oz = orow[p * 3 + 2];
        float mk = mrow[p];
        float ix = __builtin_fmaf(0.25f, ox, xb + (float)px);
        float iy = __builtin_fmaf(0.5f, oy, yb + (float)py);
        float iz = __builtin_fmaf(0.5f, oz, zb + (float)pz);
        ix = fminf(fmaxf(ix, 0.f), 36.f);
        iy = fminf(fmaxf(iy, 0.f), 36.f);
        iz = fminf(fmaxf(iz, 0.f), 36.f);
        float xf = floorf(ix), yf = floorf(iy), zf = floorf(iz);
        float fx = ix - xf, fy = iy - yf, fz = iz - zf;
        float fi = __builtin_fmaf(zf, (float)PW2, __builtin_fmaf(yf, (float)PW, xf));
        int ib = ((int)fi) << 7;                 // 128 B per voxel row (fp16)
        const char* base = volc + ib;
        uint4 r000 = *(const uint4*)(base);
        uint4 r001 = *(const uint4*)(base + 128);
        uint4 r010 = *(const uint4*)(base + PW * 128);
        uint4 r011 = *(const uint4*)(base + PW * 128 + 128);
        uint4 r100 = *(const uint4*)(base + PW2 * 128);
        uint4 r101 = *(const uint4*)(base + PW2 * 128 + 128);
        uint4 r110 = *(const uint4*)(base + (PW2 + PW) * 128);
        uint4 r111 = *(const uint4*)(base + (PW2 + PW) * 128 + 128);
        __half2 fx2 = __float2half2_rn(fx);
        __half2 fy2 = __float2half2_rn(fy);
        __half2 fz2 = __float2half2_rn(fz);
        #define TRI(comp, ci)                                                   \
        {                                                                       \
            __half2 t0 = __hfma2(fx2, __hsub2(h2(r001.comp), h2(r000.comp)), h2(r000.comp)); \
            __half2 t1 = __hfma2(fx2, __hsub2(h2(r011.comp), h2(r010.comp)), h2(r010.comp)); \
            __half2 t2 = __hfma2(fx2, __hsub2(h2(r101.comp), h2(r100.comp)), h2(r100.comp)); \
            __half2 t3 = __hfma2(fx2, __hsub2(h2(r111.comp), h2(r110.comp)), h2(r110.comp)); \
            __half2 u0 = __hfma2(fy2, __hsub2(t1, t0), t0);                     \
            __half2 u1 = __hfma2(fy2, __hsub2(t3, t2), t2);                     \
            __half2 rr = __hfma2(fz2, __hsub2(u1, u0), u0);                     \
            float2 ff = __half22float2(rr);                                     \
            acc[2 * ci + 0] = __builtin_fmaf(mk, ff.x, acc[2 * ci + 0]);        \
            acc[2 * ci + 1] = __builtin_fmaf(mk, ff.y, acc[2 * ci + 1]);        \
        }
        TRI(x, 0) TRI(y, 1) TRI(z, 2) TRI(w, 3)
        #undef TRI
    }
}

// ---- LDS sampler: region 6(z)x6(y)x8(x) rows (rr = 48z+8y+x); om preloaded ----
// Preload keeps the lgkm queue carrying ONLY volume reads during the loop.
template<int P0, int NP>
__device__ __forceinline__ void sampleL(const float* __restrict__ orow,
                                        const float* __restrict__ mrow,
                                        const char* __restrict__ volp,
                                        float xb, float yb, float zb,
                                        float* __restrict__ acc) {
    float ox[NP], oy[NP], oz[NP], mk[NP];
#pragma unroll
    for (int i = 0; i < NP; ++i) {
        ox[i] = orow[(P0 + i) * 3 + 0];
        oy[i] = orow[(P0 + i) * 3 + 1];
        oz[i] = orow[(P0 + i) * 3 + 2];
        mk[i] = mrow[P0 + i];
    }
#pragma unroll
    for (int i = 0; i < NP; ++i) {
        const int p = P0 + i;
        const int px = p % 3, py = (p / 3) % 3, pz = p / 9;
        float ix = __builtin_fmaf(0.25f, ox[i], xb + (float)px);
        float iy = __builtin_fmaf(0.5f, oy[i], yb + (float)py);
        float iz = __builtin_fmaf(0.5f, oz[i], zb + (float)pz);
        // clamp to region (1-voxel margin; equals global clamp for |off|<1)
        ix = fminf(fmaxf(ix, 0.f), 6.999f);
        iy = fminf(fmaxf(iy, 0.f), 4.999f);
        iz = fminf(fmaxf(iz, 0.f), 4.999f);
        float xf = floorf(ix), yf = floorf(iy), zf = floorf(iz);
        float fx = ix - xf, fy = iy - yf, fz = iz - zf;
        float fi = __builtin_fmaf(zf, 48.f, __builtin_fmaf(yf, 8.f, xf));
        int rr = (int)fi;
        #define RD(o) (*(const uint4*)(volp + ((rr + (o)) << 7)))
        uint4 r000 = RD(0);
        uint4 r001 = RD(1);
        uint4 r010 = RD(8);
        uint4 r011 = RD(9);
        uint4 r100 = RD(48);
        uint4 r101 = RD(49);
        uint4 r110 = RD(56);
        uint4 r111 = RD(57);
        #undef RD
        __half2 fx2 = __float2half2_rn(fx);
        __half2 fy2 = __float2half2_rn(fy);
        __half2 fz2 = __float2half2_rn(fz);
        float m = mk[i];
        #define TRI(comp, ci)                                                   \
        {                                                                       \
            __half2 t0 = __hfma2(fx2, __hsub2(h2(r001.comp), h2(r000.comp)), h2(r000.comp)); \
            __half2 t1 = __hfma2(fx2, __hsub2(h2(r011.comp), h2(r010.comp)), h2(r010.comp)); \
            __half2 t2 = __hfma2(fx2, __hsub2(h2(r101.comp), h2(r100.comp)), h2(r100.comp)); \
            __half2 t3 = __hfma2(fx2, __hsub2(h2(r111.comp), h2(r110.comp)), h2(r110.comp)); \
            __half2 u0 = __hfma2(fy2, __hsub2(t1, t0), t0);                     \
            __half2 u1 = __hfma2(fy2, __hsub2(t3, t2), t2);                     \
            __half2 rr2 = __hfma2(fz2, __hsub2(u1, u0), u0);                    \
            float2 ff = __half22float2(rr2);                                    \
            acc[2 * ci + 0] = __builtin_fmaf(m, ff.x, acc[2 * ci + 0]);         \
            acc[2 * ci + 1] = __builtin_fmaf(m, ff.y, acc[2 * ci + 1]);         \
        }
        TRI(x, 0) TRI(y, 1) TRI(z, 2) TRI(w, 3)
        #undef TRI
    }
}

// ========= K3: main — 2x2x4 tile, 4 waves; VMEM/LDS wave-specialized sampling =========
// Waves 0-1: points 0-8 via VMEM gathers (TA pipe). Waves 2-3: points 9-26 via
// LDS-staged region (LDS pipe). The two pipes run concurrently on different waves.
__global__ void __launch_bounds__(256, 2) k_main(const unsigned short* __restrict__ x1b,
                                                 const unsigned short* __restrict__ xpad,
                                                 const unsigned short* __restrict__ WcatB,
                                                 const float* __restrict__ bcat,
                                                 const unsigned short* __restrict__ outB,
                                                 const float* __restrict__ out_b,
                                                 float* __restrict__ out) {
    __shared__ float om_s[16 * OMS];             // 14592 B
    __shared__ unsigned short smb[16 * 72];      // 2304 B
    __shared__ char vol[288 * 128];              // 36864 B: 6x6x8 region rows
    __shared__ float pbuf[16 * 64];              // 4096 B: LDS-half partials
    int tid = threadIdx.x, wv = tid >> 6, lane = tid & 63;
    int quad = lane >> 4, col = lane & 15;
    // XCD swizzle over tiles: blocks sharing (blk&7) land on one XCD
    int sb = ((blockIdx.x & 7) << 8) | (blockIdx.x >> 3);
    int tw = sb & 7, th = (sb >> 3) & 15, td = sb >> 7;
    // ---- phase 0: stage 6x6x8 region (2304 x 16B units; 9 per thread) ----
    {
        const char* xp = (const char*)xpad;
#pragma unroll
        for (int k = 0; k < 3; ++k) {
            uint4 t[3];
#pragma unroll
            for (int j = 0; j < 3; ++j) {
                int u = tid + (k * 3 + j) * 256;
                int rr = u >> 3, ch = u & 7;
                int dz = rr / 48, rem = rr - dz * 48, dy = rem >> 3, dx = rem & 7;
                int pv = ((2 * td + dz) * PW + (2 * th + dy)) * PW + 4 * tw + dx;
                t[j] = *(const uint4*)(xp + ((size_t)pv << 7) + (ch << 4));
            }
#pragma unroll
            for (int j = 0; j < 3; ++j) {
                int u = tid + (k * 3 + j) * 256;
                *(uint4*)(vol + (u << 4)) = t[j];   // u*16 == rr*128 + ch*16 (linear)
            }
        }
    }
    // ---- phase 1: offset+mask GEMM (16x64)@(64x224); 14 jt tiles over 4 waves ----
    {
        int sv = vox_of(sb, col);                // lane's A-row voxel
        bf16x8 a0 = *(const bf16x8*)(x1b + (size_t)sv * 64 + quad * 8);
        bf16x8 a1 = *(const bf16x8*)(x1b + (size_t)sv * 64 + 32 + quad * 8);
        for (int jt = wv; jt < 14; jt += 4) {
            int n0 = jt * 16;
            bf16x8 b0 = *(const bf16x8*)(WcatB + (n0 + col) * 64 + quad * 8);
            bf16x8 b1 = *(const bf16x8*)(WcatB + (n0 + col) * 64 + 32 + quad * 8);
            f32x4 c = {0.f, 0.f, 0.f, 0.f};
            c = __builtin_amdgcn_mfma_f32_16x16x32_bf16(a0, b0, c, 0, 0, 0);
            c = __builtin_amdgcn_mfma_f32_16x16x32_bf16(a1, b1, c, 0, 0, 0);
            float bb = bcat[n0 + col];
            // remap feature n -> padded 28-pt slot
            int n = n0 + col, slot;
            if (n < 162) slot = n + ((n >= 81) ? 3 : 0);
            else { int n2 = n - 162; slot = 168 + n2 + ((n2 >= 27) ? 1 : 0); }
            if (n < 216) {
#pragma unroll
                for (int r = 0; r < 4; ++r)
                    om_s[(quad * 4 + r) * OMS + slot] = c[r] + bb;
            }
        }
    }
    __syncthreads();                             // covers staging AND om_s
    // ---- phase 2: softmax, replicated per voxel-half; wave handles its own 16 rows ----
    // Waves 0,2 cover voxels 0-7; waves 1,3 cover 8-15 (identical values written twice).
    {
        int row = lane >> 2, sub = lane & 3;     // 16 rows/wave, 4 lanes/row, 7 pts/lane
        int vloc = (wv & 1) * 8 + (row >> 1), g = row & 1;
        float* m = &om_s[vloc * OMS + 168 + g * 28];
        float mv[7];
        float mx = -1e30f;
#pragma unroll
        for (int i = 0; i < 7; ++i) {
            int p = sub * 7 + i;
            mv[i] = (p < 27) ? m[p] : -1e30f;
            mx = fmaxf(mx, mv[i]);
        }
        mx = fmaxf(mx, __shfl_xor(mx, 1));
        mx = fmaxf(mx, __shfl_xor(mx, 2));
        float e[7], sm = 0.f;
#pragma unroll
        for (int i = 0; i < 7; ++i) { e[i] = __expf(mv[i] - mx); sm += e[i]; }
        sm += __shfl_xor(sm, 1);
        sm += __shfl_xor(sm, 2);
        float inv = 1.f / sm;
#pragma unroll
        for (int i = 0; i < 7; ++i) {
            int p = sub * 7 + i;
            if (p < 27) m[p] = e[i] * inv;
        }
    }
    // ---- phase 3: wave-specialized sampling ----
    {
        int half = wv & 1, mode = wv >> 1;       // mode 0 = VMEM pts 0-8, 1 = LDS pts 9-26
        int v = half * 8 + (lane >> 3);          // local voxel 0..15
        int oct = lane & 7, gg = oct >> 2;       // channels oct*8..oct*8+7
        const float* orow = &om_s[v * OMS + gg * 84];
        const float* mrow = &om_s[v * OMS + 168 + gg * 28];
        float acc[8] = {0.f, 0.f, 0.f, 0.f, 0.f, 0.f, 0.f, 0.f};
        if (mode == 0) {
            int sv = vox_of(sb, v);
            float zb = (float)((sv >> 10) + 1);
            float yb = (float)(((sv >> 5) & 31) + 1);
            float xb = (float)((sv & 31) + 1);
            sampleN<0, 9>(orow, mrow, (const char*)xpad + oct * 16, xb, yb, zb, acc);
        } else {
            int vw = v & 3, vh = (v >> 2) & 1, vd = v >> 3;
            sampleL<9, 18>(orow, mrow, vol + oct * 16,
                           (float)(vw + 1), (float)(vh + 1), (float)(vd + 1), acc);
            float* pp = &pbuf[v * 64 + oct * 8];
            *(f32x4*)(pp) = *(f32x4*)(acc);
            *(f32x4*)(pp + 4) = *(f32x4*)(acc + 4);
        }
        __syncthreads();
        if (mode == 0) {                         // combine halves + pack bf16
            const float* pp = &pbuf[v * 64 + oct * 8];
            bf16x8 sb8;
#pragma unroll
            for (int k = 0; k < 8; ++k) sb8[k] = (short)f2b(acc[k] + pp[k]);
            *(bf16x8*)(smb + v * 72 + oct * 8) = sb8;
        }
    }
    __syncthreads();
    // ---- phase 4: out projection (16x64)@(64x64); wave wv does col tile wv ----
    {
        bf16x8 oa0 = *(const bf16x8*)(smb + col * 72 + quad * 8);
        bf16x8 oa1 = *(const bf16x8*)(smb + col * 72 + 32 + quad * 8);
        int n0 = wv * 16;
        bf16x8 b0 = *(const bf16x8*)(outB + (n0 + col) * 64 + quad * 8);
        bf16x8 b1 = *(const bf16x8*)(outB + (n0 + col) * 64 + 32 + quad * 8);
        f32x4 c = {0.f, 0.f, 0.f, 0.f};
        c = __builtin_amdgcn_mfma_f32_16x16x32_bf16(oa0, b0, c, 0, 0, 0);
        c = __builtin_amdgcn_mfma_f32_16x16x32_bf16(oa1, b1, c, 0, 0, 0);
        float bb = out_b[n0 + col];
        int vr[4];
#pragma unroll
        for (int r = 0; r < 4; ++r) vr[r] = vox_of(sb, quad * 4 + r);
#pragma unroll
        for (int r = 0; r < 4; ++r)
            out[(size_t)vr[r] * 64 + n0 + col] = c[r] + bb;
    }
}

extern "C" void kernel_launch(void* const* d_in, const int* in_sizes, int n_in,
                              void* d_out, int out_size, void* d_ws, size_t ws_size,
                              hipStream_t stream) {
    const float* x      = (const float*)d_in[0];
    const float* dw_w   = (const float*)d_in[1];
    const float* gn_w   = (const float*)d_in[2];
    const float* gn_b   = (const float*)d_in[3];
    const float* inp_w  = (const float*)d_in[4];
    const float* inp_b  = (const float*)d_in[5];
    const float* off_w  = (const float*)d_in[6];
    const float* off_b  = (const float*)d_in[7];
    const float* mask_w = (const float*)d_in[8];
    const float* mask_b = (const float*)d_in[9];
    const float* out_w  = (const float*)d_in[10];
    const float* out_b  = (const float*)d_in[11];

    char* B = (char*)d_ws;
    float*          partials = (float*)(B + 256);                // 64 KB region (uses 16 KB)
    unsigned short* xcb      = (unsigned short*)(B + 65792);     // 4 MB (bf16)
    unsigned short* x1b      = (unsigned short*)(B + 8454400);   // 4 MB
    unsigned short* x_tb     = (unsigned short*)(B + 12648704);  // 4 MB
    unsigned short* xpad     = (unsigned short*)(B + 16843008);  // 7.02 MB (fp16)
    unsigned short* WcatB    = (unsigned short*)(B + 30890240);  // 28 KB
    float*          bcat     = (float*)(B + 30918912);           // 1 KB
    unsigned short* inpB     = (unsigned short*)(B + 30919936);  // 8 KB
    unsigned short* outB     = (unsigned short*)(B + 30928128);  // 8 KB
    float* out = (float*)d_out;

    k_front<<<88 + 512 + 2048 + 858, 256, 0, stream>>>(x, dw_w, off_w, mask_w, off_b, mask_b,
                                                       inp_w, out_w, WcatB, bcat, inpB, outB,
                                                       x_tb, xcb, partials, xpad);
    k_mid<<<512 + 512, 256, 0, stream>>>(xcb, partials, gn_w, gn_b, x1b,
                                         x_tb, inpB, inp_b, xpad);
    k_main<<<2048, 256, 0, stream>>>(x1b, xpad, WcatB, bcat, outB, out_b, out);
}

// Round 8
// 149.759 us; speedup vs baseline: 1.2574x; 1.0202x over previous
//
#include <hip/hip_runtime.h>
#include <hip/hip_fp16.h>
#include <math.h>

#define SP 32768            // 32*32*32 voxels
#define PW 38               // padded volume width (zero ring around 34^3 logical)
#define PW2 (PW*PW)         // 1444
#define PVOX (PW*PW*PW)     // 54872
#define OMS 228             // om_s row stride (floats): 28-pt padded offs(2*84) + masks(2*28)

typedef short bf16x8 __attribute__((ext_vector_type(8)));
typedef unsigned short u16x4 __attribute__((ext_vector_type(4)));
typedef float f32x4 __attribute__((ext_vector_type(4)));

__device__ __forceinline__ unsigned short f2b(float f) {
    unsigned u = __float_as_uint(f);
    u = (u + 0x7FFFu + ((u >> 16) & 1u)) >> 16;   // RNE
    return (unsigned short)u;
}
__device__ __forceinline__ float b2f1(unsigned short s) {
    return __uint_as_float(((unsigned)s) << 16);
}
__device__ __forceinline__ __half2 h2(unsigned u) {
    return *reinterpret_cast<__half2*>(&u);
}
// block voxel tile = 2(d) x 2(h) x 4(w); tile grid = 16(d) x 16(h) x 8(w)
__device__ __forceinline__ int vox_of(int sb, int v) {
    int tw = sb & 7, th = (sb >> 3) & 15, td = sb >> 7;
    int vw = v & 3, vh = (v >> 2) & 1, vd = v >> 3;
    return (((td << 1) + vd) << 10) + (((th << 1) + vh) << 5) + (tw << 2) + vw;
}

// ====== K1: prep (bf16 B^T weights) + dwconv(x4, shfl-reduce) + ring zero ======
__global__ void k_front(const float* __restrict__ x, const float* __restrict__ dw,
                        const float* __restrict__ off_w, const float* __restrict__ mask_w,
                        const float* __restrict__ off_b, const float* __restrict__ mask_b,
                        const float* __restrict__ inp_w, const float* __restrict__ out_w,
                        unsigned short* __restrict__ WcatB, float* __restrict__ bcat,
                        unsigned short* __restrict__ inpB, unsigned short* __restrict__ outB,
                        unsigned short* __restrict__ xcb, float* __restrict__ partials,
                        unsigned short* __restrict__ xpad) {
    int bb = blockIdx.x, tid = threadIdx.x;
    if (bb < 88) {                               // ---- weight prep ----
        int idx = bb * 256 + tid;
        int j = idx >> 6, k = idx & 63;
        if (j < 224) {
            float v = 0.f;
            if (j < 162) v = off_w[k * 162 + j];
            else if (j < 216) v = mask_w[k * 54 + (j - 162)];
            WcatB[j * 64 + k] = f2b(v);
            if (k == 0) bcat[j] = (j < 162) ? off_b[j] : (j < 216 ? mask_b[j - 162] : 0.f);
        } else if (j < 288) {
            outB[(j - 224) * 64 + k] = f2b(out_w[k * 64 + (j - 224)]);
        } else {
            inpB[(j - 288) * 64 + k] = f2b(inp_w[k * 64 + (j - 288)]);
        }
        return;
    }
    if (bb < 2136) {                             // ---- dwconv 3x3x3, 4 outputs/thread ----
        int b4 = bb - 88;
        int e4 = b4 * 256 + tid;                 // group of 4 voxels along w
        int c = e4 >> 13, s4 = (e4 & 8191) << 2;
        int d = s4 >> 10, h = (s4 >> 5) & 31, w0 = s4 & 31;   // w0 in {0,4,...,28}
        const float* xs = x + (size_t)c * SP;
        const float* wt = dw + c * 27;
        float a0 = 0.f, a1 = 0.f, a2 = 0.f, a3 = 0.f;
#pragma unroll
        for (int kd = 0; kd < 3; ++kd) {
            int zz = d + kd - 1; if ((unsigned)zz >= 32u) continue;
#pragma unroll
            for (int kh = 0; kh < 3; ++kh) {
                int yy = h + kh - 1; if ((unsigned)yy >= 32u) continue;
                const float* row = xs + (zz << 10) + (yy << 5) + w0;
                float4 L = *(const float4*)row;
                float xl = (w0 > 0) ? row[-1] : 0.f;
                float xr = (w0 < 28) ? row[4] : 0.f;
                const float* wr = wt + kd * 9 + kh * 3;
                float wm = wr[0], wc = wr[1], wp = wr[2];
                a0 = __builtin_fmaf(wm, xl,  __builtin_fmaf(wc, L.x, __builtin_fmaf(wp, L.y, a0)));
                a1 = __builtin_fmaf(wm, L.x, __builtin_fmaf(wc, L.y, __builtin_fmaf(wp, L.z, a1)));
                a2 = __builtin_fmaf(wm, L.y, __builtin_fmaf(wc, L.z, __builtin_fmaf(wp, L.w, a2)));
                a3 = __builtin_fmaf(wm, L.z, __builtin_fmaf(wc, L.w, __builtin_fmaf(wp, xr,  a3)));
            }
        }
        u16x4 o4; o4[0] = f2b(a0); o4[1] = f2b(a1); o4[2] = f2b(a2); o4[3] = f2b(a3);
        *(u16x4*)(xcb + (size_t)e4 * 4) = o4;
        // wave shuffle reduction (1 barrier instead of 8)
        float s1 = a0 + a1 + a2 + a3;
        float s2 = a0 * a0 + a1 * a1 + a2 * a2 + a3 * a3;
#pragma unroll
        for (int off = 32; off > 0; off >>= 1) {
            s1 += __shfl_xor(s1, off);
            s2 += __shfl_xor(s2, off);
        }
        __shared__ float ws[8];
        int wv = tid >> 6, lane = tid & 63;
        if (lane == 0) { ws[wv * 2] = s1; ws[wv * 2 + 1] = s2; }
        __syncthreads();
        if (tid == 0) {
            partials[b4 * 2 + 0] = ws[0] + ws[2] + ws[4] + ws[6];
            partials[b4 * 2 + 1] = ws[1] + ws[3] + ws[5] + ws[7];
        }
        return;
    }
    // ---- ring zero (fp16): independent of everything else ----
    int cblk = bb - 2136;
    int j = tid >> 4, c4 = tid & 15;
    u16x4 z = {0, 0, 0, 0};
#pragma unroll
    for (int k = 0; k < 4; ++k) {
        int v = cblk * 64 + k * 16 + j;
        if (v >= PVOX) break;
        int zz = v / PW2, r = v - zz * PW2, yy = r / PW, xx = r - yy * PW;
        if (zz < 2 || zz > 33 || yy < 2 || yy > 33 || xx < 2 || xx > 33)
            *(u16x4*)(xpad + (size_t)v * 64 + c4 * 4) = z;
    }
}

// ========= K2: GN+GELU -> x1b  |  MFMA inproj (in-block transpose) -> xpad =========
__global__ void k_mid(const unsigned short* __restrict__ xcb, const float* __restrict__ partials,
                      const float* __restrict__ gn_w, const float* __restrict__ gn_b,
                      unsigned short* __restrict__ x1b,
                      const float* __restrict__ x,
                      const unsigned short* __restrict__ inpB,
                      const float* __restrict__ inp_b,
                      unsigned short* __restrict__ xpad) {
    int bb = blockIdx.x, tid = threadIdx.x;
    if (bb < 512) {                              // ---- GroupNorm(1,C)+GELU, transposed ----
        __shared__ float rs[256], rq[256];
        __shared__ unsigned short tile[64][66];
        float a = 0.f, b = 0.f;
        for (int i = tid; i < 2048; i += 256) { a += partials[2 * i]; b += partials[2 * i + 1]; }
        rs[tid] = a; rq[tid] = b;
        __syncthreads();
        for (int off = 128; off > 0; off >>= 1) {
            if (tid < off) { rs[tid] += rs[tid + off]; rq[tid] += rq[tid + off]; }
            __syncthreads();
        }
        const float Minv = 1.f / 2097152.f;
        float mu = rs[0] * Minv;
        float var = rq[0] * Minv - mu * mu;
        float rsq = rsqrtf(var + 1e-5f);
        int s0 = bb * 64;
        int row = tid >> 6, lane = tid & 63;
        for (int c = row; c < 64; c += 4) {
            float v = (b2f1(xcb[(size_t)c * SP + s0 + lane]) - mu) * rsq * gn_w[c] + gn_b[c];
            // gelu(tanh) = v * sigmoid(2t), t = 0.79788456*(v+0.044715 v^3)
            float t2 = 1.5957691216057308f * (v + 0.044715f * v * v * v);
            tile[c][lane] = f2b(v / (1.f + __expf(-t2)));
        }
        __syncthreads();
        for (int r = row; r < 64; r += 4)
            x1b[(size_t)(s0 + r) * 64 + lane] = tile[lane][r];
        return;
    }
    // ---- inproj: 4 waves x 16 voxels; transpose x in-block (x_tb eliminated) ----
    {
        __shared__ unsigned short tileT[64][72];  // [voxel][channel], 16B-aligned rows
        int s0b = (bb - 512) * 64;
        int row = tid >> 6, lane = tid & 63;
        for (int c = row; c < 64; c += 4)
            tileT[lane][c] = f2b(x[(size_t)c * SP + s0b + lane]);
        __syncthreads();
        int wv = row, quad = lane >> 4, col = lane & 15;
        int s0 = s0b + wv * 16;
        bf16x8 a0 = *(const bf16x8*)(&tileT[wv * 16 + col][quad * 8]);
        bf16x8 a1 = *(const bf16x8*)(&tileT[wv * 16 + col][32 + quad * 8]);
        int vp[4];
#pragma unroll
        for (int r = 0; r < 4; ++r) {
            int s = s0 + (quad << 2) + r;        // orig voxel (d,h,w) at 38-coord +2
            vp[r] = (((s >> 10) + 2) * PW + ((s >> 5) & 31) + 2) * PW + (s & 31) + 2;
        }
#pragma unroll
        for (int nt = 0; nt < 4; ++nt) {
            int n0 = nt * 16;
            bf16x8 b0 = *(const bf16x8*)(inpB + (n0 + col) * 64 + quad * 8);
            bf16x8 b1 = *(const bf16x8*)(inpB + (n0 + col) * 64 + 32 + quad * 8);
            f32x4 c = {0.f, 0.f, 0.f, 0.f};
            c = __builtin_amdgcn_mfma_f32_16x16x32_bf16(a0, b0, c, 0, 0, 0);
            c = __builtin_amdgcn_mfma_f32_16x16x32_bf16(a1, b1, c, 0, 0, 0);
            float bq = inp_b[n0 + col];
#pragma unroll
            for (int r = 0; r < 4; ++r)
                xpad[(size_t)vp[r] * 64 + n0 + col] =
                    __half_as_ushort(__float2half(c[r] + bq));
        }
    }
}

// ---- VMEM sampler (proven round-4 path); global coords, clamp [0,36] ----
template<int P0, int NP>
__device__ __forceinline__ void sampleN(const float* __restrict__ orow,
                                        const float* __restrict__ mrow,
                                        const char* __restrict__ volc,
                                        float xb, float yb, float zb,
                                        float* __restrict__ acc) {
#pragma unroll
    for (int i = 0; i < NP; ++i) {
        const int p = P0 + i;
        const int px = p % 3, py = (p / 3) % 3, pz = p / 9;
        float ox = orow[p * 3 + 0], oy = orow[p * 3 + 1], oz = orow[p * 3 + 2];
        float mk = mrow[p];
        float ix = __builtin_fmaf(0.25f, ox, xb + (float)px);
        float iy = __builtin_fmaf(0.5f, oy, yb + (float)py);
        float iz = __builtin_fmaf(0.5f, oz, zb + (float)pz);
        ix = fminf(fmaxf(ix, 0.f), 36.f);
        iy = fminf(fmaxf(iy, 0.f), 36.f);
        iz = fminf(fmaxf(iz, 0.f), 36.f);
        float xf = floorf(ix), yf = floorf(iy), zf = floorf(iz);
        float fx = ix - xf, fy = iy - yf, fz = iz - zf;
        float fi = __builtin_fmaf(zf, (float)PW2, __builtin_fmaf(yf, (float)PW, xf));
        int ib = ((int)fi) << 7;                 // 128 B per voxel row (fp16)
        const char* base = volc + ib;
        uint4 r000 = *(const uint4*)(base);
        uint4 r001 = *(const uint4*)(base + 128);
        uint4 r010 = *(const uint4*)(base + PW * 128);
        uint4 r011 = *(const uint4*)(base + PW * 128 + 128);
        uint4 r100 = *(const uint4*)(base + PW2 * 128);
        uint4 r101 = *(const uint4*)(base + PW2 * 128 + 128);
        uint4 r110 = *(const uint4*)(base + (PW2 + PW) * 128);
        uint4 r111 = *(const uint4*)(base + (PW2 + PW) * 128 + 128);
        __half2 fx2 = __float2half2_rn(fx);
        __half2 fy2 = __float2half2_rn(fy);
        __half2 fz2 = __float2half2_rn(fz);
        #define TRI(comp, ci)                                                   \
        {                                                                       \
            __half2 t0 = __hfma2(fx2, __hsub2(h2(r001.comp), h2(r000.comp)), h2(r000.comp)); \
            __half2 t1 = __hfma2(fx2, __hsub2(h2(r011.comp), h2(r010.comp)), h2(r010.comp)); \
            __half2 t2 = __hfma2(fx2, __hsub2(h2(r101.comp), h2(r100.comp)), h2(r100.comp)); \
            __half2 t3 = __hfma2(fx2, __hsub2(h2(r111.comp), h2(r110.comp)), h2(r110.comp)); \
            __half2 u0 = __hfma2(fy2, __hsub2(t1, t0), t0);                     \
            __half2 u1 = __hfma2(fy2, __hsub2(t3, t2), t2);                     \
            __half2 rr = __hfma2(fz2, __hsub2(u1, u0), u0);                     \
            float2 ff = __half22float2(rr);                                     \
            acc[2 * ci + 0] = __builtin_fmaf(mk, ff.x, acc[2 * ci + 0]);        \
            acc[2 * ci + 1] = __builtin_fmaf(mk, ff.y, acc[2 * ci + 1]);        \
        }
        TRI(x, 0) TRI(y, 1) TRI(z, 2) TRI(w, 3)
        #undef TRI
    }
}

// ---- LDS sampler: region 6(z)x6(y)x8(x) rows (rr = 48z+8y+x); om preloaded ----
// Preload keeps the lgkm queue carrying ONLY volume reads during the loop.
template<int P0, int NP>
__device__ __forceinline__ void sampleL(const float* __restrict__ orow,
                                        const float* __restrict__ mrow,
                                        const char* __restrict__ volp,
                                        float xb, float yb, float zb,
                                        float* __restrict__ acc) {
    float ox[NP], oy[NP], oz[NP], mk[NP];
#pragma unroll
    for (int i = 0; i < NP; ++i) {
        ox[i] = orow[(P0 + i) * 3 + 0];
        oy[i] = orow[(P0 + i) * 3 + 1];
        oz[i] = orow[(P0 + i) * 3 + 2];
        mk[i] = mrow[P0 + i];
    }
#pragma unroll
    for (int i = 0; i < NP; ++i) {
        const int p = P0 + i;
        const int px = p % 3, py = (p / 3) % 3, pz = p / 9;
        float ix = __builtin_fmaf(0.25f, ox[i], xb + (float)px);
        float iy = __builtin_fmaf(0.5f, oy[i], yb + (float)py);
        float iz = __builtin_fmaf(0.5f, oz[i], zb + (float)pz);
        // clamp to region (1-voxel margin; equals global clamp for |off|<1)
        ix = fminf(fmaxf(ix, 0.f), 6.999f);
        iy = fminf(fmaxf(iy, 0.f), 4.999f);
        iz = fminf(fmaxf(iz, 0.f), 4.999f);
        float xf = floorf(ix), yf = floorf(iy), zf = floorf(iz);
        float fx = ix - xf, fy = iy - yf, fz = iz - zf;
        float fi = __builtin_fmaf(zf, 48.f, __builtin_fmaf(yf, 8.f, xf));
        int rr = (int)fi;
        #define RD(o) (*(const uint4*)(volp + ((rr + (o)) << 7)))
        uint4 r000 = RD(0);
        uint4 r001 = RD(1);
        uint4 r010 = RD(8);
        uint4 r011 = RD(9);
        uint4 r100 = RD(48);
        uint4 r101 = RD(49);
        uint4 r110 = RD(56);
        uint4 r111 = RD(57);
        #undef RD
        __half2 fx2 = __float2half2_rn(fx);
        __half2 fy2 = __float2half2_rn(fy);
        __half2 fz2 = __float2half2_rn(fz);
        float m = mk[i];
        #define TRI(comp, ci)                                                   \
        {                                                                       \
            __half2 t0 = __hfma2(fx2, __hsub2(h2(r001.comp), h2(r000.comp)), h2(r000.comp)); \
            __half2 t1 = __hfma2(fx2, __hsub2(h2(r011.comp), h2(r010.comp)), h2(r010.comp)); \
            __half2 t2 = __hfma2(fx2, __hsub2(h2(r101.comp), h2(r100.comp)), h2(r100.comp)); \
            __half2 t3 = __hfma2(fx2, __hsub2(h2(r111.comp), h2(r110.comp)), h2(r110.comp)); \
            __half2 u0 = __hfma2(fy2, __hsub2(t1, t0), t0);                     \
            __half2 u1 = __hfma2(fy2, __hsub2(t3, t2), t2);                     \
            __half2 rr2 = __hfma2(fz2, __hsub2(u1, u0), u0);                    \
            float2 ff = __half22float2(rr2);                                    \
            acc[2 * ci + 0] = __builtin_fmaf(m, ff.x, acc[2 * ci + 0]);         \
            acc[2 * ci + 1] = __builtin_fmaf(m, ff.y, acc[2 * ci + 1]);         \
        }
        TRI(x, 0) TRI(y, 1) TRI(z, 2) TRI(w, 3)
        #undef TRI
    }
}

// ========= K3: main — 2x2x4 tile, 4 waves; VMEM/LDS wave-specialized sampling =========
// Waves 0-1: points 0-8 via VMEM gathers (TA pipe). Waves 2-3: points 9-26 via
// LDS-staged region (LDS pipe). The two pipes run concurrently on different waves.
__global__ void __launch_bounds__(256, 2) k_main(const unsigned short* __restrict__ x1b,
                                                 const unsigned short* __restrict__ xpad,
                                                 const unsigned short* __restrict__ WcatB,
                                                 const float* __restrict__ bcat,
                                                 const unsigned short* __restrict__ outB,
                                                 const float* __restrict__ out_b,
                                                 float* __restrict__ out) {
    __shared__ float om_s[16 * OMS];             // 14592 B
    __shared__ unsigned short smb[16 * 72];      // 2304 B
    __shared__ char vol[288 * 128];              // 36864 B: 6x6x8 region rows
    __shared__ float pbuf[16 * 64];              // 4096 B: LDS-half partials
    int tid = threadIdx.x, wv = tid >> 6, lane = tid & 63;
    int quad = lane >> 4, col = lane & 15;
    // XCD swizzle over tiles: blocks sharing (blk&7) land on one XCD
    int sb = ((blockIdx.x & 7) << 8) | (blockIdx.x >> 3);
    int tw = sb & 7, th = (sb >> 3) & 15, td = sb >> 7;
    // ---- phase 0: stage 6x6x8 region (2304 x 16B units; 9 per thread) ----
    {
        const char* xp = (const char*)xpad;
#pragma unroll
        for (int k = 0; k < 3; ++k) {
            uint4 t[3];
#pragma unroll
            for (int j = 0; j < 3; ++j) {
                int u = tid + (k * 3 + j) * 256;
                int rr = u >> 3, ch = u & 7;
                int dz = rr / 48, rem = rr - dz * 48, dy = rem >> 3, dx = rem & 7;
                int pv = ((2 * td + dz) * PW + (2 * th + dy)) * PW + 4 * tw + dx;
                t[j] = *(const uint4*)(xp + ((size_t)pv << 7) + (ch << 4));
            }
#pragma unroll
            for (int j = 0; j < 3; ++j) {
                int u = tid + (k * 3 + j) * 256;
                *(uint4*)(vol + (u << 4)) = t[j];   // u*16 == rr*128 + ch*16 (linear)
            }
        }
    }
    // ---- phase 1: offset+mask GEMM (16x64)@(64x224); 14 jt tiles over 4 waves ----
    {
        int sv = vox_of(sb, col);                // lane's A-row voxel
        bf16x8 a0 = *(const bf16x8*)(x1b + (size_t)sv * 64 + quad * 8);
        bf16x8 a1 = *(const bf16x8*)(x1b + (size_t)sv * 64 + 32 + quad * 8);
        for (int jt = wv; jt < 14; jt += 4) {
            int n0 = jt * 16;
            bf16x8 b0 = *(const bf16x8*)(WcatB + (n0 + col) * 64 + quad * 8);
            bf16x8 b1 = *(const bf16x8*)(WcatB + (n0 + col) * 64 + 32 + quad * 8);
            f32x4 c = {0.f, 0.f, 0.f, 0.f};
            c = __builtin_amdgcn_mfma_f32_16x16x32_bf16(a0, b0, c, 0, 0, 0);
            c = __builtin_amdgcn_mfma_f32_16x16x32_bf16(a1, b1, c, 0, 0, 0);
            float bb = bcat[n0 + col];
            // remap feature n -> padded 28-pt slot
            int n = n0 + col, slot;
            if (n < 162) slot = n + ((n >= 81) ? 3 : 0);
            else { int n2 = n - 162; slot = 168 + n2 + ((n2 >= 27) ? 1 : 0); }
            if (n < 216) {
#pragma unroll
                for (int r = 0; r < 4; ++r)
                    om_s[(quad * 4 + r) * OMS + slot] = c[r] + bb;
            }
        }
    }
    __syncthreads();                             // covers staging AND om_s
    // ---- phase 2: softmax, replicated per voxel-half; wave handles its own 16 rows ----
    // Waves 0,2 cover voxels 0-7; waves 1,3 cover 8-15 (identical values written twice).
    {
        int row = lane >> 2, sub = lane & 3;     // 16 rows/wave, 4 lanes/row, 7 pts/lane
        int vloc = (wv & 1) * 8 + (row >> 1), g = row & 1;
        float* m = &om_s[vloc * OMS + 168 + g * 28];
        float mv[7];
        float mx = -1e30f;
#pragma unroll
        for (int i = 0; i < 7; ++i) {
            int p = sub * 7 + i;
            mv[i] = (p < 27) ? m[p] : -1e30f;
            mx = fmaxf(mx, mv[i]);
        }
        mx = fmaxf(mx, __shfl_xor(mx, 1));
        mx = fmaxf(mx, __shfl_xor(mx, 2));
        float e[7], sm = 0.f;
#pragma unroll
        for (int i = 0; i < 7; ++i) { e[i] = __expf(mv[i] - mx); sm += e[i]; }
        sm += __shfl_xor(sm, 1);
        sm += __shfl_xor(sm, 2);
        float inv = 1.f / sm;
#pragma unroll
        for (int i = 0; i < 7; ++i) {
            int p = sub * 7 + i;
            if (p < 27) m[p] = e[i] * inv;
        }
    }
    // ---- phase 3: wave-specialized sampling ----
    {
        int half = wv & 1, mode = wv >> 1;       // mode 0 = VMEM pts 0-8, 1 = LDS pts 9-26
        int v = half * 8 + (lane >> 3);          // local voxel 0..15
        int oct = lane & 7, gg = oct >> 2;       // channels oct*8..oct*8+7
        const float* orow = &om_s[v * OMS + gg * 84];
        const float* mrow = &om_s[v * OMS + 168 + gg * 28];
        float acc[8] = {0.f, 0.f, 0.f, 0.f, 0.f, 0.f, 0.f, 0.f};
        if (mode == 0) {
            int sv = vox_of(sb, v);
            float zb = (float)((sv >> 10) + 1);
            float yb = (float)(((sv >> 5) & 31) + 1);
            float xb = (float)((sv & 31) + 1);
            sampleN<0, 9>(orow, mrow, (const char*)xpad + oct * 16, xb, yb, zb, acc);
        } else {
            int vw = v & 3, vh = (v >> 2) & 1, vd = v >> 3;
            sampleL<9, 18>(orow, mrow, vol + oct * 16,
                           (float)(vw + 1), (float)(vh + 1), (float)(vd + 1), acc);
            float* pp = &pbuf[v * 64 + oct * 8];
            *(f32x4*)(pp) = *(f32x4*)(acc);
            *(f32x4*)(pp + 4) = *(f32x4*)(acc + 4);
        }
        __syncthreads();
        if (mode == 0) {                         // combine halves + pack bf16
            const float* pp = &pbuf[v * 64 + oct * 8];
            bf16x8 sb8;
#pragma unroll
            for (int k = 0; k < 8; ++k) sb8[k] = (short)f2b(acc[k] + pp[k]);
            *(bf16x8*)(smb + v * 72 + oct * 8) = sb8;
        }
    }
    __syncthreads();
    // ---- phase 4: out projection (16x64)@(64x64); wave wv does col tile wv ----
    {
        bf16x8 oa0 = *(const bf16x8*)(smb + col * 72 + quad * 8);
        bf16x8 oa1 = *(const bf16x8*)(smb + col * 72 + 32 + quad * 8);
        int n0 = wv * 16;
        bf16x8 b0 = *(const bf16x8*)(outB + (n0 + col) * 64 + quad * 8);
        bf16x8 b1 = *(const bf16x8*)(outB + (n0 + col) * 64 + 32 + quad * 8);
        f32x4 c = {0.f, 0.f, 0.f, 0.f};
        c = __builtin_amdgcn_mfma_f32_16x16x32_bf16(oa0, b0, c, 0, 0, 0);
        c = __builtin_amdgcn_mfma_f32_16x16x32_bf16(oa1, b1, c, 0, 0, 0);
        float bb = out_b[n0 + col];
        int vr[4];
#pragma unroll
        for (int r = 0; r < 4; ++r) vr[r] = vox_of(sb, quad * 4 + r);
#pragma unroll
        for (int r = 0; r < 4; ++r)
            out[(size_t)vr[r] * 64 + n0 + col] = c[r] + bb;
    }
}

extern "C" void kernel_launch(void* const* d_in, const int* in_sizes, int n_in,
                              void* d_out, int out_size, void* d_ws, size_t ws_size,
                              hipStream_t stream) {
    const float* x      = (const float*)d_in[0];
    const float* dw_w   = (const float*)d_in[1];
    const float* gn_w   = (const float*)d_in[2];
    const float* gn_b   = (const float*)d_in[3];
    const float* inp_w  = (const float*)d_in[4];
    const float* inp_b  = (const float*)d_in[5];
    const float* off_w  = (const float*)d_in[6];
    const float* off_b  = (const float*)d_in[7];
    const float* mask_w = (const float*)d_in[8];
    const float* mask_b = (const float*)d_in[9];
    const float* out_w  = (const float*)d_in[10];
    const float* out_b  = (const float*)d_in[11];

    char* B = (char*)d_ws;
    float*          partials = (float*)(B + 256);                // 64 KB region (uses 16 KB)
    unsigned short* xcb      = (unsigned short*)(B + 65792);     // 4 MB (bf16)
    unsigned short* x1b      = (unsigned short*)(B + 8454400);   // 4 MB
    unsigned short* xpad     = (unsigned short*)(B + 16843008);  // 7.02 MB (fp16)
    unsigned short* WcatB    = (unsigned short*)(B + 30890240);  // 28 KB
    float*          bcat     = (float*)(B + 30918912);           // 1 KB
    unsigned short* inpB     = (unsigned short*)(B + 30919936);  // 8 KB
    unsigned short* outB     = (unsigned short*)(B + 30928128);  // 8 KB
    float* out = (float*)d_out;

    k_front<<<88 + 2048 + 858, 256, 0, stream>>>(x, dw_w, off_w, mask_w, off_b, mask_b,
                                                 inp_w, out_w, WcatB, bcat, inpB, outB,
                                                 xcb, partials, xpad);
    k_mid<<<512 + 512, 256, 0, stream>>>(xcb, partials, gn_w, gn_b, x1b,
                                         x, inpB, inp_b, xpad);
    k_main<<<2048, 256, 0, stream>>>(x1b, xpad, WcatB, bcat, outB, out_b, out);
}

// Round 9
// 148.234 us; speedup vs baseline: 1.2703x; 1.0103x over previous
//
#include <hip/hip_runtime.h>
#include <hip/hip_fp16.h>
#include <math.h>

#define SP 32768            // 32*32*32 voxels
#define PW 38               // padded volume width (zero ring around 34^3 logical)
#define PW2 (PW*PW)         // 1444
#define PVOX (PW*PW*PW)     // 54872
#define OMS 228             // om_s row stride (floats): 28-pt padded offs(2*84) + masks(2*28)

typedef short bf16x8 __attribute__((ext_vector_type(8)));
typedef unsigned short u16x4 __attribute__((ext_vector_type(4)));
typedef float f32x4 __attribute__((ext_vector_type(4)));

__device__ __forceinline__ unsigned short f2b(float f) {
    unsigned u = __float_as_uint(f);
    u = (u + 0x7FFFu + ((u >> 16) & 1u)) >> 16;   // RNE
    return (unsigned short)u;
}
__device__ __forceinline__ float b2f1(unsigned short s) {
    return __uint_as_float(((unsigned)s) << 16);
}
__device__ __forceinline__ __half2 h2(unsigned u) {
    return *reinterpret_cast<__half2*>(&u);
}
// block voxel tile = 2(d) x 2(h) x 4(w); tile grid = 16(d) x 16(h) x 8(w)
__device__ __forceinline__ int vox_of(int sb, int v) {
    int tw = sb & 7, th = (sb >> 3) & 15, td = sb >> 7;
    int vw = v & 3, vh = (v >> 2) & 1, vd = v >> 3;
    return (((td << 1) + vd) << 10) + (((th << 1) + vh) << 5) + (tw << 2) + vw;
}

// ====== K1: ALL independent work in one launch ======
// blocks [0,72): weight prep | [72,2120): dwconv | [2120,2632): inproj | rest: ring zero
__global__ void k_front(const float* __restrict__ x, const float* __restrict__ dw,
                        const float* __restrict__ off_w, const float* __restrict__ mask_w,
                        const float* __restrict__ off_b, const float* __restrict__ mask_b,
                        const float* __restrict__ inp_w, const float* __restrict__ inp_b,
                        const float* __restrict__ out_w,
                        unsigned short* __restrict__ WcatB, float* __restrict__ bcat,
                        unsigned short* __restrict__ outB,
                        unsigned short* __restrict__ xcb, float* __restrict__ partials,
                        unsigned short* __restrict__ xpad) {
    int bb = blockIdx.x, tid = threadIdx.x;
    if (bb < 72) {                               // ---- weight prep (j < 288) ----
        int idx = bb * 256 + tid;
        int j = idx >> 6, k = idx & 63;
        if (j < 224) {
            float v = 0.f;
            if (j < 162) v = off_w[k * 162 + j];
            else if (j < 216) v = mask_w[k * 54 + (j - 162)];
            WcatB[j * 64 + k] = f2b(v);
            if (k == 0) bcat[j] = (j < 162) ? off_b[j] : (j < 216 ? mask_b[j - 162] : 0.f);
        } else {
            outB[(j - 224) * 64 + k] = f2b(out_w[k * 64 + (j - 224)]);
        }
        return;
    }
    if (bb < 2120) {                             // ---- dwconv 3x3x3, 4 outputs/thread ----
        int b4 = bb - 72;
        int e4 = b4 * 256 + tid;                 // group of 4 voxels along w
        int c = e4 >> 13, s4 = (e4 & 8191) << 2;
        int d = s4 >> 10, h = (s4 >> 5) & 31, w0 = s4 & 31;   // w0 in {0,4,...,28}
        const float* xs = x + (size_t)c * SP;
        const float* wt = dw + c * 27;
        float a0 = 0.f, a1 = 0.f, a2 = 0.f, a3 = 0.f;
#pragma unroll
        for (int kd = 0; kd < 3; ++kd) {
            int zz = d + kd - 1; if ((unsigned)zz >= 32u) continue;
#pragma unroll
            for (int kh = 0; kh < 3; ++kh) {
                int yy = h + kh - 1; if ((unsigned)yy >= 32u) continue;
                const float* row = xs + (zz << 10) + (yy << 5) + w0;
                float4 L = *(const float4*)row;
                float xl = (w0 > 0) ? row[-1] : 0.f;
                float xr = (w0 < 28) ? row[4] : 0.f;
                const float* wr = wt + kd * 9 + kh * 3;
                float wm = wr[0], wc = wr[1], wp = wr[2];
                a0 = __builtin_fmaf(wm, xl,  __builtin_fmaf(wc, L.x, __builtin_fmaf(wp, L.y, a0)));
                a1 = __builtin_fmaf(wm, L.x, __builtin_fmaf(wc, L.y, __builtin_fmaf(wp, L.z, a1)));
                a2 = __builtin_fmaf(wm, L.y, __builtin_fmaf(wc, L.z, __builtin_fmaf(wp, L.w, a2)));
                a3 = __builtin_fmaf(wm, L.z, __builtin_fmaf(wc, L.w, __builtin_fmaf(wp, xr,  a3)));
            }
        }
        u16x4 o4; o4[0] = f2b(a0); o4[1] = f2b(a1); o4[2] = f2b(a2); o4[3] = f2b(a3);
        *(u16x4*)(xcb + (size_t)e4 * 4) = o4;
        // wave shuffle reduction (1 barrier)
        float s1 = a0 + a1 + a2 + a3;
        float s2 = a0 * a0 + a1 * a1 + a2 * a2 + a3 * a3;
#pragma unroll
        for (int off = 32; off > 0; off >>= 1) {
            s1 += __shfl_xor(s1, off);
            s2 += __shfl_xor(s2, off);
        }
        __shared__ float ws[8];
        int wv = tid >> 6, lane = tid & 63;
        if (lane == 0) { ws[wv * 2] = s1; ws[wv * 2 + 1] = s2; }
        __syncthreads();
        if (tid == 0) {
            partials[b4 * 2 + 0] = ws[0] + ws[2] + ws[4] + ws[6];
            partials[b4 * 2 + 1] = ws[1] + ws[3] + ws[5] + ws[7];
        }
        return;
    }
    if (bb < 2632) {                             // ---- inproj: self-staged weights ----
        __shared__ unsigned short tileT[64][72];  // [voxel][channel] bf16
        __shared__ unsigned short inpT[64 * 65];  // [in_ch][out_ch] bf16, pad-65 rows
        int s0b = (bb - 2120) * 64;
        int row = tid >> 6, lane = tid & 63;
        for (int c = row; c < 64; c += 4) {
            tileT[lane][c] = f2b(x[(size_t)c * SP + s0b + lane]);
            inpT[c * 65 + lane] = f2b(inp_w[(size_t)c * 64 + lane]);
        }
        __syncthreads();
        int wv = row, quad = lane >> 4, col = lane & 15;
        int s0 = s0b + wv * 16;
        bf16x8 a0 = *(const bf16x8*)(&tileT[wv * 16 + col][quad * 8]);
        bf16x8 a1 = *(const bf16x8*)(&tileT[wv * 16 + col][32 + quad * 8]);
        int vp[4];
#pragma unroll
        for (int r = 0; r < 4; ++r) {
            int s = s0 + (quad << 2) + r;        // orig voxel (d,h,w) at 38-coord +2
            vp[r] = (((s >> 10) + 2) * PW + ((s >> 5) & 31) + 2) * PW + (s & 31) + 2;
        }
#pragma unroll
        for (int nt = 0; nt < 4; ++nt) {
            int n0 = nt * 16;
            bf16x8 b0, b1;
#pragma unroll
            for (int t = 0; t < 8; ++t) {
                b0[t] = (short)inpT[(quad * 8 + t) * 65 + (n0 + col)];
                b1[t] = (short)inpT[(32 + quad * 8 + t) * 65 + (n0 + col)];
            }
            f32x4 c = {0.f, 0.f, 0.f, 0.f};
            c = __builtin_amdgcn_mfma_f32_16x16x32_bf16(a0, b0, c, 0, 0, 0);
            c = __builtin_amdgcn_mfma_f32_16x16x32_bf16(a1, b1, c, 0, 0, 0);
            float bq = inp_b[n0 + col];
#pragma unroll
            for (int r = 0; r < 4; ++r)
                xpad[(size_t)vp[r] * 64 + n0 + col] =
                    __half_as_ushort(__float2half(c[r] + bq));
        }
        return;
    }
    // ---- ring zero (fp16): independent of everything else ----
    int cblk = bb - 2632;
    int j = tid >> 4, c4 = tid & 15;
    u16x4 z = {0, 0, 0, 0};
#pragma unroll
    for (int k = 0; k < 4; ++k) {
        int v = cblk * 64 + k * 16 + j;
        if (v >= PVOX) break;
        int zz = v / PW2, r = v - zz * PW2, yy = r / PW, xx = r - yy * PW;
        if (zz < 2 || zz > 33 || yy < 2 || yy > 33 || xx < 2 || xx > 33)
            *(u16x4*)(xpad + (size_t)v * 64 + c4 * 4) = z;
    }
}

// ---- VMEM sampler (proven round-4 path); global coords, clamp [0,36] ----
template<int P0, int NP>
__device__ __forceinline__ void sampleN(const float* __restrict__ orow,
                                        const float* __restrict__ mrow,
                                        const char* __restrict__ volc,
                                        float xb, float yb, float zb,
                                        float* __restrict__ acc) {
#pragma unroll
    for (int i = 0; i < NP; ++i) {
        const int p = P0 + i;
        const int px = p % 3, py = (p / 3) % 3, pz = p / 9;
        float ox = orow[p * 3 + 0], oy = orow[p * 3 + 1], oz = orow[p * 3 + 2];
        float mk = mrow[p];
        float ix = __builtin_fmaf(0.25f, ox, xb + (float)px);
        float iy = __builtin_fmaf(0.5f, oy, yb + (float)py);
        float iz = __builtin_fmaf(0.5f, oz, zb + (float)pz);
        ix = fminf(fmaxf(ix, 0.f), 36.f);
        iy = fminf(fmaxf(iy, 0.f), 36.f);
        iz = fminf(fmaxf(iz, 0.f), 36.f);
        float xf = floorf(ix), yf = floorf(iy), zf = floorf(iz);
        float fx = ix - xf, fy = iy - yf, fz = iz - zf;
        float fi = __builtin_fmaf(zf, (float)PW2, __builtin_fmaf(yf, (float)PW, xf));
        int ib = ((int)fi) << 7;                 // 128 B per voxel row (fp16)
        const char* base = volc + ib;
        uint4 r000 = *(const uint4*)(base);
        uint4 r001 = *(const uint4*)(base + 128);
        uint4 r010 = *(const uint4*)(base + PW * 128);
        uint4 r011 = *(const uint4*)(base + PW * 128 + 128);
        uint4 r100 = *(const uint4*)(base + PW2 * 128);
        uint4 r101 = *(const uint4*)(base + PW2 * 128 + 128);
        uint4 r110 = *(const uint4*)(base + (PW2 + PW) * 128);
        uint4 r111 = *(const uint4*)(base + (PW2 + PW) * 128 + 128);
        __half2 fx2 = __float2half2_rn(fx);
        __half2 fy2 = __float2half2_rn(fy);
        __half2 fz2 = __float2half2_rn(fz);
        #define TRI(comp, ci)                                                   \
        {                                                                       \
            __half2 t0 = __hfma2(fx2, __hsub2(h2(r001.comp), h2(r000.comp)), h2(r000.comp)); \
            __half2 t1 = __hfma2(fx2, __hsub2(h2(r011.comp), h2(r010.comp)), h2(r010.comp)); \
            __half2 t2 = __hfma2(fx2, __hsub2(h2(r101.comp), h2(r100.comp)), h2(r100.comp)); \
            __half2 t3 = __hfma2(fx2, __hsub2(h2(r111.comp), h2(r110.comp)), h2(r110.comp)); \
            __half2 u0 = __hfma2(fy2, __hsub2(t1, t0), t0);                     \
            __half2 u1 = __hfma2(fy2, __hsub2(t3, t2), t2);                     \
            __half2 rr = __hfma2(fz2, __hsub2(u1, u0), u0);                     \
            float2 ff = __half22float2(rr);                                     \
            acc[2 * ci + 0] = __builtin_fmaf(mk, ff.x, acc[2 * ci + 0]);        \
            acc[2 * ci + 1] = __builtin_fmaf(mk, ff.y, acc[2 * ci + 1]);        \
        }
        TRI(x, 0) TRI(y, 1) TRI(z, 2) TRI(w, 3)
        #undef TRI
    }
}

// ---- LDS sampler: region 6(z)x6(y)x8(x) rows (rr = 48z+8y+x); om preloaded ----
template<int P0, int NP>
__device__ __forceinline__ void sampleL(const float* __restrict__ orow,
                                        const float* __restrict__ mrow,
                                        const char* __restrict__ volp,
                                        float xb, float yb, float zb,
                                        float* __restrict__ acc) {
    float ox[NP], oy[NP], oz[NP], mk[NP];
#pragma unroll
    for (int i = 0; i < NP; ++i) {
        ox[i] = orow[(P0 + i) * 3 + 0];
        oy[i] = orow[(P0 + i) * 3 + 1];
        oz[i] = orow[(P0 + i) * 3 + 2];
        mk[i] = mrow[P0 + i];
    }
#pragma unroll
    for (int i = 0; i < NP; ++i) {
        const int p = P0 + i;
        const int px = p % 3, py = (p / 3) % 3, pz = p / 9;
        float ix = __builtin_fmaf(0.25f, ox[i], xb + (float)px);
        float iy = __builtin_fmaf(0.5f, oy[i], yb + (float)py);
        float iz = __builtin_fmaf(0.5f, oz[i], zb + (float)pz);
        // clamp to region (1-voxel margin; equals global clamp for |off|<1)
        ix = fminf(fmaxf(ix, 0.f), 6.999f);
        iy = fminf(fmaxf(iy, 0.f), 4.999f);
        iz = fminf(fmaxf(iz, 0.f), 4.999f);
        float xf = floorf(ix), yf = floorf(iy), zf = floorf(iz);
        float fx = ix - xf, fy = iy - yf, fz = iz - zf;
        float fi = __builtin_fmaf(zf, 48.f, __builtin_fmaf(yf, 8.f, xf));
        int rr = (int)fi;
        #define RD(o) (*(const uint4*)(volp + ((rr + (o)) << 7)))
        uint4 r000 = RD(0);
        uint4 r001 = RD(1);
        uint4 r010 = RD(8);
        uint4 r011 = RD(9);
        uint4 r100 = RD(48);
        uint4 r101 = RD(49);
        uint4 r110 = RD(56);
        uint4 r111 = RD(57);
        #undef RD
        __half2 fx2 = __float2half2_rn(fx);
        __half2 fy2 = __float2half2_rn(fy);
        __half2 fz2 = __float2half2_rn(fz);
        float m = mk[i];
        #define TRI(comp, ci)                                                   \
        {                                                                       \
            __half2 t0 = __hfma2(fx2, __hsub2(h2(r001.comp), h2(r000.comp)), h2(r000.comp)); \
            __half2 t1 = __hfma2(fx2, __hsub2(h2(r011.comp), h2(r010.comp)), h2(r010.comp)); \
            __half2 t2 = __hfma2(fx2, __hsub2(h2(r101.comp), h2(r100.comp)), h2(r100.comp)); \
            __half2 t3 = __hfma2(fx2, __hsub2(h2(r111.comp), h2(r110.comp)), h2(r110.comp)); \
            __half2 u0 = __hfma2(fy2, __hsub2(t1, t0), t0);                     \
            __half2 u1 = __hfma2(fy2, __hsub2(t3, t2), t2);                     \
            __half2 rr2 = __hfma2(fz2, __hsub2(u1, u0), u0);                    \
            float2 ff = __half22float2(rr2);                                    \
            acc[2 * ci + 0] = __builtin_fmaf(m, ff.x, acc[2 * ci + 0]);         \
            acc[2 * ci + 1] = __builtin_fmaf(m, ff.y, acc[2 * ci + 1]);         \
        }
        TRI(x, 0) TRI(y, 1) TRI(z, 2) TRI(w, 3)
        #undef TRI
    }
}

// ========= K2: main — fused GN+GELU + hybrid-sampled deformable conv =========
__global__ void __launch_bounds__(256, 2) k_main(const unsigned short* __restrict__ xcb,
                                                 const float* __restrict__ partials,
                                                 const float* __restrict__ gn_w,
                                                 const float* __restrict__ gn_b,
                                                 const unsigned short* __restrict__ xpad,
                                                 const unsigned short* __restrict__ WcatB,
                                                 const float* __restrict__ bcat,
                                                 const unsigned short* __restrict__ outB,
                                                 const float* __restrict__ out_b,
                                                 float* __restrict__ out) {
    __shared__ float om_s[16 * OMS];             // 14592 B
    __shared__ unsigned short smb[16 * 72];      // 2304 B
    __shared__ char vol[288 * 128];              // 36864 B: 6x6x8 region rows
    __shared__ float pbuf[16 * 64];              // 4096 B: LDS-half partials
    __shared__ float gnw_s[64], gnb_s[64], ws[8];
    int tid = threadIdx.x, wv = tid >> 6, lane = tid & 63;
    int quad = lane >> 4, col = lane & 15;
    // XCD swizzle over tiles: blocks sharing (blk&7) land on one XCD
    int sb = ((blockIdx.x & 7) << 8) | (blockIdx.x >> 3);
    int tw = sb & 7, th = (sb >> 3) & 15, td = sb >> 7;
    // ---- phase 0: stage 6x6x8 region (2304 x 16B units; 9 per thread) ----
    {
        const char* xp = (const char*)xpad;
#pragma unroll
        for (int k = 0; k < 3; ++k) {
            uint4 t[3];
#pragma unroll
            for (int j = 0; j < 3; ++j) {
                int u = tid + (k * 3 + j) * 256;
                int rr = u >> 3, ch = u & 7;
                int dz = rr / 48, rem = rr - dz * 48, dy = rem >> 3, dx = rem & 7;
                int pv = ((2 * td + dz) * PW + (2 * th + dy)) * PW + 4 * tw + dx;
                t[j] = *(const uint4*)(xp + ((size_t)pv << 7) + (ch << 4));
            }
#pragma unroll
            for (int j = 0; j < 3; ++j) {
                int u = tid + (k * 3 + j) * 256;
                *(uint4*)(vol + (u << 4)) = t[j];   // u*16 == rr*128 + ch*16 (linear)
            }
        }
    }
    // ---- phase 0.5: GN stats (2048 partial pairs) + gn params to LDS ----
    {
        if (tid < 64) { gnw_s[tid] = gn_w[tid]; gnb_s[tid] = gn_b[tid]; }
        float a = 0.f, b = 0.f;
#pragma unroll
        for (int i = 0; i < 4; ++i) {
            float4 t = *(const float4*)(partials + 4 * (tid + i * 256));
            a += t.x + t.z;
            b += t.y + t.w;
        }
#pragma unroll
        for (int off = 32; off > 0; off >>= 1) {
            a += __shfl_xor(a, off);
            b += __shfl_xor(b, off);
        }
        if (lane == 0) { ws[wv * 2] = a; ws[wv * 2 + 1] = b; }
    }
    __syncthreads();                             // #A: ws, gn LDS, vol staging
    const float Minv = 1.f / 2097152.f;
    float mu = (ws[0] + ws[2] + ws[4] + ws[6]) * Minv;
    float var = (ws[1] + ws[3] + ws[5] + ws[7]) * Minv - mu * mu;
    float rsq = rsqrtf(var + 1e-5f);
    // ---- phase 1: GN+GELU A-fragments (from xcb) + offset/mask GEMM ----
    {
        int sv = vox_of(sb, col);                // lane's A-row voxel
        bf16x8 a0, a1;
#pragma unroll
        for (int t = 0; t < 8; ++t) {
            int c0 = quad * 8 + t, c1 = 32 + quad * 8 + t;
            float v0 = (b2f1(xcb[(size_t)c0 * SP + sv]) - mu) * rsq * gnw_s[c0] + gnb_s[c0];
            float q0 = 1.5957691216057308f * (v0 + 0.044715f * v0 * v0 * v0);
            a0[t] = (short)f2b(v0 / (1.f + __expf(-q0)));
            float v1 = (b2f1(xcb[(size_t)c1 * SP + sv]) - mu) * rsq * gnw_s[c1] + gnb_s[c1];
            float q1 = 1.5957691216057308f * (v1 + 0.044715f * v1 * v1 * v1);
            a1[t] = (short)f2b(v1 / (1.f + __expf(-q1)));
        }
        for (int jt = wv; jt < 14; jt += 4) {
            int n0 = jt * 16;
            bf16x8 b0 = *(const bf16x8*)(WcatB + (n0 + col) * 64 + quad * 8);
            bf16x8 b1 = *(const bf16x8*)(WcatB + (n0 + col) * 64 + 32 + quad * 8);
            f32x4 c = {0.f, 0.f, 0.f, 0.f};
            c = __builtin_amdgcn_mfma_f32_16x16x32_bf16(a0, b0, c, 0, 0, 0);
            c = __builtin_amdgcn_mfma_f32_16x16x32_bf16(a1, b1, c, 0, 0, 0);
            float bb = bcat[n0 + col];
            // remap feature n -> padded 28-pt slot
            int n = n0 + col, slot;
            if (n < 162) slot = n + ((n >= 81) ? 3 : 0);
            else { int n2 = n - 162; slot = 168 + n2 + ((n2 >= 27) ? 1 : 0); }
            if (n < 216) {
#pragma unroll
                for (int r = 0; r < 4; ++r)
                    om_s[(quad * 4 + r) * OMS + slot] = c[r] + bb;
            }
        }
    }
    __syncthreads();                             // #B: om_s ready
    // ---- phase 2: softmax, replicated per voxel-half; in-wave consumption ----
    {
        int row = lane >> 2, sub = lane & 3;     // 16 rows/wave, 4 lanes/row, 7 pts/lane
        int vloc = (wv & 1) * 8 + (row >> 1), g = row & 1;
        float* m = &om_s[vloc * OMS + 168 + g * 28];
        float mv[7];
        float mx = -1e30f;
#pragma unroll
        for (int i = 0; i < 7; ++i) {
            int p = sub * 7 + i;
            mv[i] = (p < 27) ? m[p] : -1e30f;
            mx = fmaxf(mx, mv[i]);
        }
        mx = fmaxf(mx, __shfl_xor(mx, 1));
        mx = fmaxf(mx, __shfl_xor(mx, 2));
        float e[7], sm = 0.f;
#pragma unroll
        for (int i = 0; i < 7; ++i) { e[i] = __expf(mv[i] - mx); sm += e[i]; }
        sm += __shfl_xor(sm, 1);
        sm += __shfl_xor(sm, 2);
        float inv = 1.f / sm;
#pragma unroll
        for (int i = 0; i < 7; ++i) {
            int p = sub * 7 + i;
            if (p < 27) m[p] = e[i] * inv;
        }
    }
    // ---- phase 3: wave-specialized sampling (VMEM pts 0-8 | LDS pts 9-26) ----
    {
        int half = wv & 1, mode = wv >> 1;
        int v = half * 8 + (lane >> 3);          // local voxel 0..15
        int oct = lane & 7, gg = oct >> 2;       // channels oct*8..oct*8+7
        const float* orow = &om_s[v * OMS + gg * 84];
        const float* mrow = &om_s[v * OMS + 168 + gg * 28];
        float acc[8] = {0.f, 0.f, 0.f, 0.f, 0.f, 0.f, 0.f, 0.f};
        if (mode == 0) {
            int sv = vox_of(sb, v);
            float zb = (float)((sv >> 10) + 1);
            float yb = (float)(((sv >> 5) & 31) + 1);
            float xb = (float)((sv & 31) + 1);
            sampleN<0, 9>(orow, mrow, (const char*)xpad + oct * 16, xb, yb, zb, acc);
        } else {
            int vw = v & 3, vh = (v >> 2) & 1, vd = v >> 3;
            sampleL<9, 18>(orow, mrow, vol + oct * 16,
                           (float)(vw + 1), (float)(vh + 1), (float)(vd + 1), acc);
            float* pp = &pbuf[v * 64 + oct * 8];
            *(f32x4*)(pp) = *(f32x4*)(acc);
            *(f32x4*)(pp + 4) = *(f32x4*)(acc + 4);
        }
        __syncthreads();                         // #C: pbuf ready
        if (mode == 0) {                         // combine halves + pack bf16
            const float* pp = &pbuf[v * 64 + oct * 8];
            bf16x8 sb8;
#pragma unroll
            for (int k = 0; k < 8; ++k) sb8[k] = (short)f2b(acc[k] + pp[k]);
            *(bf16x8*)(smb + v * 72 + oct * 8) = sb8;
        }
    }
    __syncthreads();                             // #D: smb ready
    // ---- phase 4: out projection (16x64)@(64x64); wave wv does col tile wv ----
    {
        bf16x8 oa0 = *(const bf16x8*)(smb + col * 72 + quad * 8);
        bf16x8 oa1 = *(const bf16x8*)(smb + col * 72 + 32 + quad * 8);
        int n0 = wv * 16;
        bf16x8 b0 = *(const bf16x8*)(outB + (n0 + col) * 64 + quad * 8);
        bf16x8 b1 = *(const bf16x8*)(outB + (n0 + col) * 64 + 32 + quad * 8);
        f32x4 c = {0.f, 0.f, 0.f, 0.f};
        c = __builtin_amdgcn_mfma_f32_16x16x32_bf16(oa0, b0, c, 0, 0, 0);
        c = __builtin_amdgcn_mfma_f32_16x16x32_bf16(oa1, b1, c, 0, 0, 0);
        float bb = out_b[n0 + col];
        int vr[4];
#pragma unroll
        for (int r = 0; r < 4; ++r) vr[r] = vox_of(sb, quad * 4 + r);
#pragma unroll
        for (int r = 0; r < 4; ++r)
            out[(size_t)vr[r] * 64 + n0 + col] = c[r] + bb;
    }
}

extern "C" void kernel_launch(void* const* d_in, const int* in_sizes, int n_in,
                              void* d_out, int out_size, void* d_ws, size_t ws_size,
                              hipStream_t stream) {
    const float* x      = (const float*)d_in[0];
    const float* dw_w   = (const float*)d_in[1];
    const float* gn_w   = (const float*)d_in[2];
    const float* gn_b   = (const float*)d_in[3];
    const float* inp_w  = (const float*)d_in[4];
    const float* inp_b  = (const float*)d_in[5];
    const float* off_w  = (const float*)d_in[6];
    const float* off_b  = (const float*)d_in[7];
    const float* mask_w = (const float*)d_in[8];
    const float* mask_b = (const float*)d_in[9];
    const float* out_w  = (const float*)d_in[10];
    const float* out_b  = (const float*)d_in[11];

    char* B = (char*)d_ws;
    float*          partials = (float*)(B + 256);                // 16 KB used
    unsigned short* xcb      = (unsigned short*)(B + 65792);     // 4 MB (bf16)
    unsigned short* xpad     = (unsigned short*)(B + 16843008);  // 7.02 MB (fp16)
    unsigned short* WcatB    = (unsigned short*)(B + 30890240);  // 28 KB
    float*          bcat     = (float*)(B + 30918912);           // 1 KB
    unsigned short* outB     = (unsigned short*)(B + 30928128);  // 8 KB
    float* out = (float*)d_out;

    k_front<<<72 + 2048 + 512 + 858, 256, 0, stream>>>(x, dw_w, off_w, mask_w, off_b, mask_b,
                                                       inp_w, inp_b, out_w, WcatB, bcat, outB,
                                                       xcb, partials, xpad);
    k_main<<<2048, 256, 0, stream>>>(xcb, partials, gn_w, gn_b, xpad,
                                     WcatB, bcat, outB, out_b, out);
}